// Round 2
// 2315.223 us; speedup vs baseline: 1.1931x; 1.1931x over previous
//
#include <hip/hip_runtime.h>
#include <math.h>

#define NTOK   4096
#define DIM    1024
#define H3     3072
#define HMLP   4096
#define NEXP   16
#define CAP    640
#define HCHUNK 1024
#define LSCALE 2048.0f
#define INV_LSCALE (1.0f / 2048.0f)

typedef _Float16 half8 __attribute__((ext_vector_type(8)));
typedef __attribute__((ext_vector_type(4))) float floatx4;
typedef __attribute__((ext_vector_type(8))) ushort us8;

// ---- workspace layout (float-element offsets) ----
#define F_QKV_HI   ((size_t)0)
#define F_QKV_LO   ((size_t)6291456)
#define F_XN_HI    ((size_t)12582912)
#define F_XN_LO    ((size_t)14680064)
#define F_H1       ((size_t)0)
#define F_EOUT     ((size_t)0)
// q/k/v fp16 hi/lo (overlays old fp32 qbuf/kbuf/vbuf region 16777216..29360128)
#define F_Q16_HI   ((size_t)16777216)
#define F_K16_HI   ((size_t)18874368)
#define F_V16_HI   ((size_t)20971520)
#define F_Q16_LO   ((size_t)23068672)
#define F_K16_LO   ((size_t)25165824)
#define F_V16_LO   ((size_t)27262976)
// V^T hi/lo (overlays xn hi/lo, dead after qkv GEMM)
#define F_VT_HI    ((size_t)12582912)
#define F_VT_LO    ((size_t)14680064)
#define F_AO_HI    ((size_t)29360128)
#define F_AO_LO    ((size_t)31457280)
#define F_XF_HI    ((size_t)33554432)
#define F_XF_LO    ((size_t)35651584)
#define F_WQKV_HI  ((size_t)37748736)
#define F_WQKV_LO  ((size_t)39321600)
#define F_WAIN_HI  ((size_t)40894464)
#define F_WAIN_LO  ((size_t)42467328)
#define F_WAOUT_HI ((size_t)44040192)
#define F_WAOUT_LO ((size_t)44564480)
#define F_WR1_HI   ((size_t)45088768)
#define F_WR1_LO   ((size_t)47185920)
// phase3 overlay (phase1/2 contents dead)
#define F_EXPIN    ((size_t)16777216)
#define F_MLP1T    ((size_t)22020096)
#define F_MID      ((size_t)30408704)
#define F_MLP2T    ((size_t)35651584)
// persistent
#define F_X1       ((size_t)49283072)
#define F_XF       ((size_t)53477376)
#define F_PROBS    ((size_t)57671680)
#define F_INDS     ((size_t)57679872)
#define F_KEEP     ((size_t)57688064)
#define F_FLAT     ((size_t)57696256)

__device__ __forceinline__ ushort f2h(float f) {
    _Float16 h = (_Float16)f;
    union { _Float16 h; ushort u; } c; c.h = h; return c.u;
}
__device__ __forceinline__ float h2f(ushort u) {
    union { ushort u; _Float16 h; } c; c.u = u; return (float)c.h;
}
__device__ __forceinline__ float gelu_exact(float x) {
    return 0.5f * x * (1.0f + erff(x * 0.7071067811865475f));
}

// ---------------- split fp32 -> (hi fp16, lo fp16 scaled by 2048) ----------------
__global__ __launch_bounds__(256) void split_f32(const float* __restrict__ x,
                                                 ushort* __restrict__ hi,
                                                 ushort* __restrict__ lo, int n4) {
    int i = blockIdx.x * 256 + threadIdx.x;
    if (i >= n4) return;
    float4 v = ((const float4*)x)[i];
    float vv[4] = {v.x, v.y, v.z, v.w};
    ushort h[4], l[4];
#pragma unroll
    for (int e = 0; e < 4; e++) {
        h[e] = f2h(vv[e]);
        l[e] = f2h((vv[e] - h2f(h[e])) * LSCALE);
    }
    ((ushort4*)hi)[i] = make_ushort4(h[0], h[1], h[2], h[3]);
    ((ushort4*)lo)[i] = make_ushort4(l[0], l[1], l[2], l[3]);
}

// ---------------- LayerNorm: optional fp32 / fp16-hi / fp16-lo outputs ----------------
__global__ __launch_bounds__(256) void ln_kernel(const float* __restrict__ x,
                                                 const float* __restrict__ g,
                                                 const float* __restrict__ b,
                                                 float* __restrict__ yf,
                                                 ushort* __restrict__ yhi,
                                                 ushort* __restrict__ ylo) {
    __shared__ float red0[4], red1[4], bc[2];
    const size_t t = blockIdx.x;
    const float* row = x + t * DIM;
    float v[4];
    float s = 0.f, s2 = 0.f;
#pragma unroll
    for (int i = 0; i < 4; i++) {
        float vv = row[threadIdx.x + i * 256];
        v[i] = vv; s += vv; s2 += vv * vv;
    }
#pragma unroll
    for (int off = 32; off > 0; off >>= 1) {
        s  += __shfl_down(s, off);
        s2 += __shfl_down(s2, off);
    }
    const int lane = threadIdx.x & 63, wid = threadIdx.x >> 6;
    if (lane == 0) { red0[wid] = s; red1[wid] = s2; }
    __syncthreads();
    if (threadIdx.x == 0) {
        float S = red0[0] + red0[1] + red0[2] + red0[3];
        float S2 = red1[0] + red1[1] + red1[2] + red1[3];
        float mean = S * (1.0f / DIM);
        float var = S2 * (1.0f / DIM) - mean * mean;
        bc[0] = mean; bc[1] = rsqrtf(var + 1e-5f);
    }
    __syncthreads();
    const float mean = bc[0], r = bc[1];
#pragma unroll
    for (int i = 0; i < 4; i++) {
        int idx = threadIdx.x + i * 256;
        float val = (v[i] - mean) * r * g[idx] + b[idx];
        size_t o = t * DIM + idx;
        if (yf) yf[o] = val;
        if (yhi) {
            ushort h = f2h(val);
            yhi[o] = h;
            if (ylo) ylo[o] = f2h((val - h2f(h)) * LSCALE);
        }
    }
}

// ---------------- fp16 MFMA NT GEMM; SPLIT = scaled hi/lo (fp32-accurate) ----------------
template<bool SPLIT>
__global__ __launch_bounds__(256) void gemm_ht(
    const ushort* __restrict__ Ahi, const ushort* __restrict__ Alo, int lda, long long sA,
    const ushort* __restrict__ Bhi, const ushort* __restrict__ Blo, int ldb, long long sB,
    const float* __restrict__ bias, long long sBias,
    const float* __restrict__ resid, int ldr,
    float* __restrict__ outf, ushort* __restrict__ outhi, ushort* __restrict__ outlo,
    int ldc, long long sC, int Kdim, int act, int accum) {
    __shared__ ushort sAh[128][40];
    __shared__ ushort sBh[128][40];
    __shared__ ushort sAl[SPLIT ? 128 : 1][40];
    __shared__ ushort sBl[SPLIT ? 128 : 1][40];
    const int z = blockIdx.z;
    Ahi += (size_t)z * sA; Bhi += (size_t)z * sB;
    if constexpr (SPLIT) { Alo += (size_t)z * sA; Blo += (size_t)z * sB; }
    if (bias) bias += (size_t)z * sBias;
    if (outf) outf += (size_t)z * sC;
    if (outhi) outhi += (size_t)z * sC;
    if (outlo) outlo += (size_t)z * sC;

    const int tid = threadIdx.x;
    const int row0 = blockIdx.y * 128, col0 = blockIdx.x * 128;
    const int sr = tid >> 2, skq = (tid & 3) * 8;
    const int lane = tid & 63;
    const int m = lane & 15, half = lane >> 4;
    const int w = tid >> 6;
    const int ar0 = (w >> 1) * 64, bc0 = (w & 1) * 64;

    floatx4 acc[4][4];
    floatx4 acc2[SPLIT ? 4 : 1][SPLIT ? 4 : 1];
#pragma unroll
    for (int i = 0; i < 4; i++)
#pragma unroll
        for (int j = 0; j < 4; j++) acc[i][j] = (floatx4){0.f, 0.f, 0.f, 0.f};
    if constexpr (SPLIT) {
#pragma unroll
        for (int i = 0; i < 4; i++)
#pragma unroll
            for (int j = 0; j < 4; j++) acc2[i][j] = (floatx4){0.f, 0.f, 0.f, 0.f};
    }

    for (int k0 = 0; k0 < Kdim; k0 += 32) {
        uint4 a0 = *(const uint4*)(Ahi + (size_t)(row0 + sr) * lda + k0 + skq);
        uint4 a1 = *(const uint4*)(Ahi + (size_t)(row0 + sr + 64) * lda + k0 + skq);
        uint4 b0 = *(const uint4*)(Bhi + (size_t)(col0 + sr) * ldb + k0 + skq);
        uint4 b1 = *(const uint4*)(Bhi + (size_t)(col0 + sr + 64) * ldb + k0 + skq);
        uint4 a2, a3, b2, b3;
        if constexpr (SPLIT) {
            a2 = *(const uint4*)(Alo + (size_t)(row0 + sr) * lda + k0 + skq);
            a3 = *(const uint4*)(Alo + (size_t)(row0 + sr + 64) * lda + k0 + skq);
            b2 = *(const uint4*)(Blo + (size_t)(col0 + sr) * ldb + k0 + skq);
            b3 = *(const uint4*)(Blo + (size_t)(col0 + sr + 64) * ldb + k0 + skq);
        }
        __syncthreads();
        *(uint4*)&sAh[sr][skq] = a0;
        *(uint4*)&sAh[sr + 64][skq] = a1;
        *(uint4*)&sBh[sr][skq] = b0;
        *(uint4*)&sBh[sr + 64][skq] = b1;
        if constexpr (SPLIT) {
            *(uint4*)&sAl[sr][skq] = a2;
            *(uint4*)&sAl[sr + 64][skq] = a3;
            *(uint4*)&sBl[sr][skq] = b2;
            *(uint4*)&sBl[sr + 64][skq] = b3;
        }
        __syncthreads();
        half8 fa[4], fb[4], fal[4], fbl[4];
#pragma unroll
        for (int i = 0; i < 4; i++) fa[i] = *(const half8*)&sAh[ar0 + i * 16 + m][half * 8];
#pragma unroll
        for (int j = 0; j < 4; j++) fb[j] = *(const half8*)&sBh[bc0 + j * 16 + m][half * 8];
        if constexpr (SPLIT) {
#pragma unroll
            for (int i = 0; i < 4; i++) fal[i] = *(const half8*)&sAl[ar0 + i * 16 + m][half * 8];
#pragma unroll
            for (int j = 0; j < 4; j++) fbl[j] = *(const half8*)&sBl[bc0 + j * 16 + m][half * 8];
        }
#pragma unroll
        for (int i = 0; i < 4; i++)
#pragma unroll
            for (int j = 0; j < 4; j++) {
                acc[i][j] = __builtin_amdgcn_mfma_f32_16x16x32_f16(fa[i], fb[j], acc[i][j], 0, 0, 0);
                if constexpr (SPLIT) {
                    acc2[i][j] = __builtin_amdgcn_mfma_f32_16x16x32_f16(fa[i], fbl[j], acc2[i][j], 0, 0, 0);
                    acc2[i][j] = __builtin_amdgcn_mfma_f32_16x16x32_f16(fal[i], fb[j], acc2[i][j], 0, 0, 0);
                }
            }
    }
    // epilogue: C/D layout col=lane&15, row=(lane>>4)*4+reg
#pragma unroll
    for (int i = 0; i < 4; i++) {
#pragma unroll
        for (int j = 0; j < 4; j++) {
            const int col = col0 + bc0 + j * 16 + m;
            const float bv = bias ? bias[col] : 0.f;
#pragma unroll
            for (int r = 0; r < 4; r++) {
                const int row = row0 + ar0 + i * 16 + half * 4 + r;
                float v = acc[i][j][r];
                if constexpr (SPLIT) v += acc2[i][j][r] * INV_LSCALE;
                v += bv;
                if (resid) v += resid[(size_t)row * ldr + col];
                if (accum) v += outf[(size_t)row * ldc + col];
                if (act) v = gelu_exact(v);
                const size_t o = (size_t)row * ldc + col;
                if (outf) outf[o] = v;
                if (outhi) {
                    ushort h = f2h(v);
                    outhi[o] = h;
                    if (outlo) outlo[o] = f2h((v - h2f(h)) * LSCALE);
                }
            }
        }
    }
}

// ---------------- transpose fp32 [R,C] -> fp16 [C,R], batched ----------------
__global__ __launch_bounds__(256) void transpose_h(const float* __restrict__ in, long long sIn, int ldin,
                                                   ushort* __restrict__ out, long long sOut, int ldout) {
    __shared__ float t[32][33];
    const int z = blockIdx.z;
    in += (size_t)z * sIn; out += (size_t)z * sOut;
    const int cx = threadIdx.x & 31, ry = threadIdx.x >> 5;
    const int r0 = blockIdx.y * 32, c0 = blockIdx.x * 32;
#pragma unroll
    for (int rr = 0; rr < 4; rr++)
        t[ry + rr * 8][cx] = in[(size_t)(r0 + ry + rr * 8) * ldin + c0 + cx];
    __syncthreads();
#pragma unroll
    for (int rr = 0; rr < 4; rr++)
        out[(size_t)(c0 + ry + rr * 8) * ldout + r0 + cx] = f2h(t[cx][ry + rr * 8]);
}

// ---------------- V^T builder: v_hi/v_lo [4096][1024] -> vT [64 bh][64 d][1024 s] ----------------
__global__ __launch_bounds__(256) void vtrans_kernel(const ushort* __restrict__ vhi,
                                                     const ushort* __restrict__ vlo,
                                                     ushort* __restrict__ vthi,
                                                     ushort* __restrict__ vtlo) {
    __shared__ ushort th[32][72], tl[32][72];
    const int bh = blockIdx.y, b = bh >> 4, h = bh & 15;
    const int s0 = blockIdx.x * 32;
    const int t = threadIdx.x;
    {
        const int s = t >> 3, d0 = (t & 7) * 8;
        const size_t src = ((size_t)(b * 1024 + s0 + s)) * 1024 + h * 64 + d0;
        *(uint4*)&th[s][d0] = *(const uint4*)&vhi[src];
        *(uint4*)&tl[s][d0] = *(const uint4*)&vlo[src];
    }
    __syncthreads();
    {
        const int d = t >> 2, soff = (t & 3) * 8;
        us8 rh, rl;
#pragma unroll
        for (int e = 0; e < 8; e++) { rh[e] = th[soff + e][d]; rl[e] = tl[soff + e][d]; }
        const size_t dst = (size_t)bh * 65536 + (size_t)d * 1024 + s0 + soff;
        *(us8*)&vthi[dst] = rh;
        *(us8*)&vtlo[dst] = rl;
    }
}

// ---------------- causal flash attention, split fp16 MFMA (fp32-accurate) ----------------
// 128 q-rows/block, 4 waves x 32 rows, K-tiles of 64. Q/K/V^T fragments loaded
// direct from global in MFMA layout; P goes through wave-private swizzled LDS.
__global__ __launch_bounds__(256, 2) void attn_mfma(
        const ushort* __restrict__ qh_, const ushort* __restrict__ ql_,
        const ushort* __restrict__ kh_, const ushort* __restrict__ kl_,
        const ushort* __restrict__ vth_, const ushort* __restrict__ vtl_,
        ushort* __restrict__ ao_hi, ushort* __restrict__ ao_lo) {
    __shared__ ushort plds[4][2][2048];   // [wave][hi/lo][32 rows x 64 cols, xor-swizzled]
    const int bh = blockIdx.y;
    const int b = bh >> 4;
    const int qt = 7 - blockIdx.x;        // high-work tiles dispatch first
    const int tid = threadIdx.x;
    const int w = tid >> 6, lane = tid & 63;
    const int m = lane & 15, hq = lane >> 4;
    const int wrow = qt * 128 + w * 32;   // global q-row base of this wave (within b)
    const size_t cbase = ((size_t)b * 1024) * 1024 + (size_t)(bh & 15) * 64;
    const size_t vtbase = (size_t)bh * 65536;

    // Q fragments (persistent): lane holds Q[wrow+i*16+m][kk*32+hq*8 ..+7]
    half8 qfh[2][2], qfl[2][2];
#pragma unroll
    for (int i = 0; i < 2; i++)
#pragma unroll
        for (int kk = 0; kk < 2; kk++) {
            const size_t o = cbase + (size_t)(wrow + i * 16 + m) * 1024 + kk * 32 + hq * 8;
            qfh[i][kk] = *(const half8*)&qh_[o];
            qfl[i][kk] = *(const half8*)&ql_[o];
        }

    floatx4 accO[2][4], accO2[2][4];
#pragma unroll
    for (int i = 0; i < 2; i++)
#pragma unroll
        for (int d = 0; d < 4; d++) {
            accO[i][d] = (floatx4){0.f, 0.f, 0.f, 0.f};
            accO2[i][d] = (floatx4){0.f, 0.f, 0.f, 0.f};
        }
    float mx[2][4], ls[2][4];
#pragma unroll
    for (int i = 0; i < 2; i++)
#pragma unroll
        for (int r = 0; r < 4; r++) { mx[i][r] = -3.0e38f; ls[i][r] = 0.f; }

    const int ntiles = (wrow + 31) / 64 + 1;   // per-wave causal tile count (no barriers)
    for (int t = 0; t < ntiles; t++) {
        const int j0 = t * 64;
        // ---- QK^T: S = Qh*Kh + (Qh*Kl + Ql*Kh)/2048 ----
        floatx4 accS[2][4], accS2[2][4];
#pragma unroll
        for (int i = 0; i < 2; i++)
#pragma unroll
            for (int jf = 0; jf < 4; jf++) {
                accS[i][jf] = (floatx4){0.f, 0.f, 0.f, 0.f};
                accS2[i][jf] = (floatx4){0.f, 0.f, 0.f, 0.f};
            }
#pragma unroll
        for (int kk = 0; kk < 2; kk++) {
            half8 kfh[4], kfl[4];
#pragma unroll
            for (int jf = 0; jf < 4; jf++) {
                const size_t o = cbase + (size_t)(j0 + jf * 16 + m) * 1024 + kk * 32 + hq * 8;
                kfh[jf] = *(const half8*)&kh_[o];
                kfl[jf] = *(const half8*)&kl_[o];
            }
#pragma unroll
            for (int i = 0; i < 2; i++)
#pragma unroll
                for (int jf = 0; jf < 4; jf++) {
                    accS[i][jf] = __builtin_amdgcn_mfma_f32_16x16x32_f16(qfh[i][kk], kfh[jf], accS[i][jf], 0, 0, 0);
                    accS2[i][jf] = __builtin_amdgcn_mfma_f32_16x16x32_f16(qfh[i][kk], kfl[jf], accS2[i][jf], 0, 0, 0);
                    accS2[i][jf] = __builtin_amdgcn_mfma_f32_16x16x32_f16(qfl[i][kk], kfh[jf], accS2[i][jf], 0, 0, 0);
                }
        }
        // ---- combine, scale, causal mask ----
        const bool diag = (j0 + 63 > wrow);
        float p[2][4][4];
#pragma unroll
        for (int i = 0; i < 2; i++)
#pragma unroll
            for (int jf = 0; jf < 4; jf++)
#pragma unroll
                for (int r = 0; r < 4; r++) {
                    float s = (accS[i][jf][r] + accS2[i][jf][r] * INV_LSCALE) * 0.125f;
                    if (diag && (j0 + jf * 16 + m > wrow + i * 16 + hq * 4 + r)) s = -3.0e38f;
                    p[i][jf][r] = s;
                }
        // ---- online softmax per row; rows live in the same (hq,r) lanes as O ----
#pragma unroll
        for (int i = 0; i < 2; i++)
#pragma unroll
            for (int r = 0; r < 4; r++) {
                float tm = fmaxf(fmaxf(p[i][0][r], p[i][1][r]), fmaxf(p[i][2][r], p[i][3][r]));
#pragma unroll
                for (int off = 8; off > 0; off >>= 1) tm = fmaxf(tm, __shfl_xor(tm, off));
                const float mn = fmaxf(mx[i][r], tm);
                const float c = __expf(mx[i][r] - mn);
                mx[i][r] = mn;
                float rs = 0.f;
#pragma unroll
                for (int jf = 0; jf < 4; jf++) {
                    const float e = __expf(p[i][jf][r] - mn);
                    p[i][jf][r] = e;
                    rs += e;
                }
#pragma unroll
                for (int off = 8; off > 0; off >>= 1) rs += __shfl_xor(rs, off);
                ls[i][r] = ls[i][r] * c + rs;
#pragma unroll
                for (int d = 0; d < 4; d++) { accO[i][d][r] *= c; accO2[i][d][r] *= c; }
            }
        // ---- P -> LDS (hi/lo, xor-swizzled rows) ----
#pragma unroll
        for (int i = 0; i < 2; i++)
#pragma unroll
            for (int jf = 0; jf < 4; jf++)
#pragma unroll
                for (int r = 0; r < 4; r++) {
                    const int row = i * 16 + hq * 4 + r;
                    const int idx = row * 64 + ((jf * 16 + m) ^ ((row & 7) << 3));
                    const float pv = p[i][jf][r];
                    const ushort hh = f2h(pv);
                    plds[w][0][idx] = hh;
                    plds[w][1][idx] = f2h((pv - h2f(hh)) * LSCALE);
                }
        // ---- PV: O += Ph*Vh + (Ph*Vl + Pl*Vh)/2048 ----
#pragma unroll
        for (int kk = 0; kk < 2; kk++) {
            half8 pfh[2], pfl[2], vfh[4], vfl[4];
#pragma unroll
            for (int i = 0; i < 2; i++) {
                const int row = i * 16 + m;
                const int idx = row * 64 + ((kk * 32 + hq * 8) ^ ((row & 7) << 3));
                pfh[i] = *(const half8*)&plds[w][0][idx];
                pfl[i] = *(const half8*)&plds[w][1][idx];
            }
#pragma unroll
            for (int d = 0; d < 4; d++) {
                const size_t o = vtbase + (size_t)(d * 16 + m) * 1024 + j0 + kk * 32 + hq * 8;
                vfh[d] = *(const half8*)&vth_[o];
                vfl[d] = *(const half8*)&vtl_[o];
            }
#pragma unroll
            for (int i = 0; i < 2; i++)
#pragma unroll
                for (int d = 0; d < 4; d++) {
                    accO[i][d] = __builtin_amdgcn_mfma_f32_16x16x32_f16(pfh[i], vfh[d], accO[i][d], 0, 0, 0);
                    accO2[i][d] = __builtin_amdgcn_mfma_f32_16x16x32_f16(pfh[i], vfl[d], accO2[i][d], 0, 0, 0);
                    accO2[i][d] = __builtin_amdgcn_mfma_f32_16x16x32_f16(pfl[i], vfh[d], accO2[i][d], 0, 0, 0);
                }
        }
    }
    // ---- epilogue: normalize + write hi/lo ----
#pragma unroll
    for (int i = 0; i < 2; i++)
#pragma unroll
        for (int r = 0; r < 4; r++) {
            const float inv = 1.f / ls[i][r];
            const size_t rb = cbase + (size_t)(wrow + i * 16 + hq * 4 + r) * 1024;
#pragma unroll
            for (int d = 0; d < 4; d++) {
                const float v = (accO[i][d][r] + accO2[i][d][r] * INV_LSCALE) * inv;
                const ushort hh = f2h(v);
                const size_t o = rb + d * 16 + m;
                ao_hi[o] = hh;
                ao_lo[o] = f2h((v - h2f(hh)) * LSCALE);
            }
        }
}

// ---------------- router second GEMM + top-2 + softmax probs (pure fp32) ----------------
__global__ __launch_bounds__(256) void router2_kernel(const float* __restrict__ h1,
                                                      const float* __restrict__ w2,
                                                      const float* __restrict__ b2,
                                                      float* __restrict__ logits_out,
                                                      float* __restrict__ probs,
                                                      int* __restrict__ inds) {
    __shared__ float red[16][4];
    __shared__ float lg[16];
    const int t = blockIdx.x;
    const float* hrow = h1 + (size_t)t * HMLP;
    float acc[16];
#pragma unroll
    for (int m = 0; m < 16; m++) acc[m] = 0.f;
    for (int i = 0; i < 16; i++) {
        int kk = threadIdx.x + i * 256;
        float hv = hrow[kk];
#pragma unroll
        for (int m = 0; m < 16; m++) acc[m] = fmaf(hv, w2[m * HMLP + kk], acc[m]);
    }
#pragma unroll
    for (int m = 0; m < 16; m++)
#pragma unroll
        for (int off = 32; off > 0; off >>= 1) acc[m] += __shfl_down(acc[m], off);
    const int lane = threadIdx.x & 63, wid = threadIdx.x >> 6;
    if (lane == 0) {
#pragma unroll
        for (int m = 0; m < 16; m++) red[m][wid] = acc[m];
    }
    __syncthreads();
    if (threadIdx.x < 16) {
        float v = red[threadIdx.x][0] + red[threadIdx.x][1] + red[threadIdx.x][2] + red[threadIdx.x][3]
                  + b2[threadIdx.x];
        lg[threadIdx.x] = v;
        logits_out[(size_t)t * 16 + threadIdx.x] = v;
    }
    __syncthreads();
    if (threadIdx.x == 0) {
        int i0 = 0; float v0 = lg[0];
        for (int m = 1; m < 16; m++) if (lg[m] > v0) { v0 = lg[m]; i0 = m; }
        int i1 = -1; float v1 = -3.4e38f;
        for (int m = 0; m < 16; m++) if (m != i0 && lg[m] > v1) { v1 = lg[m]; i1 = m; }
        float e1 = expf(v1 - v0);
        float den = 1.f + e1;
        inds[2 * t] = i0; inds[2 * t + 1] = i1;
        probs[2 * t] = 1.f / den; probs[2 * t + 1] = e1 / den;
    }
}

// ---------------- capacity scan ----------------
__global__ __launch_bounds__(256) void scan_kernel(const int* __restrict__ inds,
                                                   int* __restrict__ keep,
                                                   int* __restrict__ flat) {
    __shared__ int counts[256][16];
    const int t = threadIdx.x;
#pragma unroll
    for (int e = 0; e < 16; e++) counts[t][e] = 0;
    const int base = t * 32;
    for (int i = 0; i < 32; i++) counts[t][inds[base + i]]++;
    __syncthreads();
    if (t < 16) {
        int run = 0;
        for (int c = 0; c < 256; c++) { int tmp = counts[c][t]; counts[c][t] = run; run += tmp; }
    }
    __syncthreads();
    for (int i = 0; i < 32; i++) {
        int e = inds[base + i];
        int p = counts[t][e]++;
        keep[base + i] = (p < CAP) ? 1 : 0;
        flat[base + i] = e * CAP + p;
    }
}

// ---------------- scatter tokens (fp32 xf -> fp16 expert_in) ----------------
__global__ __launch_bounds__(256) void scatter_kernel(const float* __restrict__ xf,
                                                      const int* __restrict__ keep,
                                                      const int* __restrict__ flat,
                                                      ushort* __restrict__ expert_in) {
    const int e = blockIdx.x;
    if (!keep[e]) return;
    const int token = e >> 1;
    const float* src = xf + (size_t)token * DIM;
    ushort* dst = expert_in + (size_t)flat[e] * DIM;
#pragma unroll
    for (int i = 0; i < 4; i++) dst[threadIdx.x + i * 256] = f2h(src[threadIdx.x + i * 256]);
}

// ---------------- combine ----------------
__global__ __launch_bounds__(256) void combine_kernel(const float* __restrict__ x1,
                                                      const float* __restrict__ xf,
                                                      const float* __restrict__ eout,
                                                      const float* __restrict__ probs,
                                                      const int* __restrict__ keep,
                                                      const int* __restrict__ flat,
                                                      float* __restrict__ out) {
    const int t = blockIdx.x;
    const int k0 = keep[2 * t], k1 = keep[2 * t + 1];
    const float p0 = probs[2 * t], p1 = probs[2 * t + 1];
    const size_t f0 = (size_t)flat[2 * t] * DIM, f1 = (size_t)flat[2 * t + 1] * DIM;
    const bool has = (k0 || k1);
    const size_t base = (size_t)t * DIM;
#pragma unroll
    for (int i = 0; i < 4; i++) {
        const int idx = threadIdx.x + i * 256;
        float mo;
        if (has) {
            mo = 0.f;
            if (k0) mo += p0 * eout[f0 + idx];
            if (k1) mo += p1 * eout[f1 + idx];
        } else {
            mo = xf[base + idx];
        }
        out[base + idx] = x1[base + idx] + mo;
    }
}

extern "C" void kernel_launch(void* const* d_in, const int* in_sizes, int n_in,
                              void* d_out, int out_size, void* d_ws, size_t ws_size,
                              hipStream_t stream) {
    const float* x          = (const float*)d_in[0];
    const float* ln1_g      = (const float*)d_in[1];
    const float* ln1_b      = (const float*)d_in[2];
    const float* qkv_w      = (const float*)d_in[3];
    const float* qkv_b      = (const float*)d_in[4];
    const float* attn_in_w  = (const float*)d_in[5];
    const float* attn_in_b  = (const float*)d_in[6];
    const float* attn_out_w = (const float*)d_in[7];
    const float* attn_out_b = (const float*)d_in[8];
    const float* ln2_g      = (const float*)d_in[9];
    const float* ln2_b      = (const float*)d_in[10];
    const float* r_w1       = (const float*)d_in[11];
    const float* r_b1       = (const float*)d_in[12];
    const float* r_w2       = (const float*)d_in[13];
    const float* r_b2       = (const float*)d_in[14];
    const float* mlp1       = (const float*)d_in[15];
    const float* mlp2       = (const float*)d_in[16];

    float* ws = (float*)d_ws;
    ushort* qkv_hi   = (ushort*)(ws + F_QKV_HI);
    ushort* qkv_lo   = (ushort*)(ws + F_QKV_LO);
    ushort* xn_hi    = (ushort*)(ws + F_XN_HI);
    ushort* xn_lo    = (ushort*)(ws + F_XN_LO);
    float*  h1       = ws + F_H1;
    float*  eout     = ws + F_EOUT;
    ushort* q_hi     = (ushort*)(ws + F_Q16_HI);
    ushort* q_lo     = (ushort*)(ws + F_Q16_LO);
    ushort* v_hi     = (ushort*)(ws + F_V16_HI);
    ushort* v_lo     = (ushort*)(ws + F_V16_LO);
    ushort* k_hi     = (ushort*)(ws + F_K16_HI);
    ushort* k_lo     = (ushort*)(ws + F_K16_LO);
    ushort* vt_hi    = (ushort*)(ws + F_VT_HI);
    ushort* vt_lo    = (ushort*)(ws + F_VT_LO);
    ushort* ao_hi    = (ushort*)(ws + F_AO_HI);
    ushort* ao_lo    = (ushort*)(ws + F_AO_LO);
    ushort* xf_hi    = (ushort*)(ws + F_XF_HI);
    ushort* xf_lo    = (ushort*)(ws + F_XF_LO);
    ushort* wqkv_hi  = (ushort*)(ws + F_WQKV_HI);
    ushort* wqkv_lo  = (ushort*)(ws + F_WQKV_LO);
    ushort* wain_hi  = (ushort*)(ws + F_WAIN_HI);
    ushort* wain_lo  = (ushort*)(ws + F_WAIN_LO);
    ushort* waout_hi = (ushort*)(ws + F_WAOUT_HI);
    ushort* waout_lo = (ushort*)(ws + F_WAOUT_LO);
    ushort* wr1_hi   = (ushort*)(ws + F_WR1_HI);
    ushort* wr1_lo   = (ushort*)(ws + F_WR1_LO);
    ushort* expert_in= (ushort*)(ws + F_EXPIN);
    ushort* mlp1t    = (ushort*)(ws + F_MLP1T);
    ushort* mid      = (ushort*)(ws + F_MID);
    ushort* mlp2t    = (ushort*)(ws + F_MLP2T);
    float*  x1       = ws + F_X1;
    float*  xf       = ws + F_XF;
    float*  probs    = ws + F_PROBS;
    int*    inds     = (int*)(ws + F_INDS);
    int*    keep     = (int*)(ws + F_KEEP);
    int*    flat     = (int*)(ws + F_FLAT);

    float* out        = (float*)d_out;
    float* logits_out = out + (size_t)NTOK * DIM;

    // weight splits (fp16 hi + scaled lo)
    split_f32<<<(3145728 / 4 + 255) / 256, 256, 0, stream>>>(qkv_w, wqkv_hi, wqkv_lo, 3145728 / 4);
    split_f32<<<(3145728 / 4 + 255) / 256, 256, 0, stream>>>(attn_in_w, wain_hi, wain_lo, 3145728 / 4);
    split_f32<<<(1048576 / 4 + 255) / 256, 256, 0, stream>>>(attn_out_w, waout_hi, waout_lo, 1048576 / 4);
    split_f32<<<(4194304 / 4 + 255) / 256, 256, 0, stream>>>(r_w1, wr1_hi, wr1_lo, 4194304 / 4);

    // 1. LN1 -> xn hi/lo
    ln_kernel<<<NTOK, 256, 0, stream>>>(x, ln1_g, ln1_b, nullptr, xn_hi, xn_lo);
    // 2. qkv = xn @ qkv_w.T + qkv_b   (split, out hi/lo)
    gemm_ht<true><<<dim3(H3 / 128, NTOK / 128, 1), 256, 0, stream>>>(
        xn_hi, xn_lo, DIM, 0, wqkv_hi, wqkv_lo, DIM, 0, qkv_b, 0,
        nullptr, 0, nullptr, qkv_hi, qkv_lo, H3, 0, DIM, 0, 0);
    // 3. q/k/v in-projections, batched z=3 (split, out fp16 hi/lo directly)
    gemm_ht<true><<<dim3(DIM / 128, NTOK / 128, 3), 256, 0, stream>>>(
        qkv_hi, qkv_lo, H3, 1024, wain_hi, wain_lo, DIM, 1048576, attn_in_b, 1024,
        nullptr, 0, nullptr, q_hi, q_lo, DIM, 4194304, DIM, 0, 0);
    // 3b. build V^T hi/lo per (b,h) for the PV B-operand
    vtrans_kernel<<<dim3(32, 64), 256, 0, stream>>>(v_hi, v_lo, vt_hi, vt_lo);
    // 4. MFMA flash attention -> ao hi/lo
    attn_mfma<<<dim3(8, 64), 256, 0, stream>>>(q_hi, q_lo, k_hi, k_lo, vt_hi, vt_lo, ao_hi, ao_lo);
    // 5. x1 = x + ao @ attn_out_w.T + b  (split, out fp32)
    gemm_ht<true><<<dim3(DIM / 128, NTOK / 128, 1), 256, 0, stream>>>(
        ao_hi, ao_lo, DIM, 0, waout_hi, waout_lo, DIM, 0, attn_out_b, 0,
        x, DIM, x1, nullptr, nullptr, DIM, 0, DIM, 0, 0);
    // 6. LN2 -> xf fp32 + hi/lo
    ln_kernel<<<NTOK, 256, 0, stream>>>(x1, ln2_g, ln2_b, xf, xf_hi, xf_lo);
    // 7. h1 = gelu(xf @ r_w1.T + r_b1)  (split, out fp32)
    gemm_ht<true><<<dim3(HMLP / 128, NTOK / 128, 1), 256, 0, stream>>>(
        xf_hi, xf_lo, DIM, 0, wr1_hi, wr1_lo, DIM, 0, r_b1, 0,
        nullptr, 0, h1, nullptr, nullptr, HMLP, 0, DIM, 1, 0);
    // 8. router logits + top-2 (fp32)
    router2_kernel<<<NTOK, 256, 0, stream>>>(h1, r_w2, r_b2, logits_out, probs, inds);
    // 9. capacity scan
    scan_kernel<<<1, 256, 0, stream>>>(inds, keep, flat);
    // 10. scatter (fp32 xf -> fp16 expert buffers)
    scatter_kernel<<<NTOK * 2, 256, 0, stream>>>(xf, keep, flat, expert_in);
    // 11. expert FFN, fp16 MFMA, H chunked (transpose weights per chunk)
    for (int c = 0; c < HMLP / HCHUNK; c++) {
        transpose_h<<<dim3(32, 32, NEXP), 256, 0, stream>>>(
            mlp1 + (size_t)c * HCHUNK, (long long)DIM * HMLP, HMLP, mlp1t, 1048576, DIM);
        gemm_ht<false><<<dim3(HCHUNK / 128, CAP / 128, NEXP), 256, 0, stream>>>(
            expert_in, nullptr, DIM, 655360, mlp1t, nullptr, DIM, 1048576, nullptr, 0,
            nullptr, 0, nullptr, mid, nullptr, HCHUNK, 655360, DIM, 1, 0);
        transpose_h<<<dim3(32, 32, NEXP), 256, 0, stream>>>(
            mlp2 + (size_t)c * HCHUNK * DIM, (long long)HMLP * DIM, DIM, mlp2t, 1048576, HCHUNK);
        gemm_ht<false><<<dim3(DIM / 128, CAP / 128, NEXP), 256, 0, stream>>>(
            mid, nullptr, HCHUNK, 655360, mlp2t, nullptr, HCHUNK, 1048576, nullptr, 0,
            nullptr, 0, eout, nullptr, nullptr, DIM, 655360, HCHUNK, 0, c > 0);
    }
    // 12. combine + residual
    combine_kernel<<<NTOK, 256, 0, stream>>>(x1, xf, eout, probs, keep, flat, out);
}

// Round 4
// 2283.388 us; speedup vs baseline: 1.2097x; 1.0139x over previous
//
#include <hip/hip_runtime.h>
#include <math.h>

#define NTOK   4096
#define DIM    1024
#define H3     3072
#define HMLP   4096
#define NEXP   16
#define CAP    640
#define HCHUNK 1024
#define LSCALE 2048.0f
#define INV_LSCALE (1.0f / 2048.0f)

typedef _Float16 half8 __attribute__((ext_vector_type(8)));
typedef __attribute__((ext_vector_type(4))) float floatx4;
typedef __attribute__((ext_vector_type(8))) ushort us8;

// ---- workspace layout (float-element offsets) ----
#define F_QKV_HI   ((size_t)0)
#define F_QKV_LO   ((size_t)6291456)
#define F_XN_HI    ((size_t)12582912)
#define F_XN_LO    ((size_t)14680064)
#define F_H1       ((size_t)0)
#define F_EOUT     ((size_t)0)
// q/k/v fp16 hi/lo (overlays old fp32 qbuf/kbuf/vbuf region 16777216..29360128)
#define F_Q16_HI   ((size_t)16777216)
#define F_K16_HI   ((size_t)18874368)
#define F_V16_HI   ((size_t)20971520)
#define F_Q16_LO   ((size_t)23068672)
#define F_K16_LO   ((size_t)25165824)
#define F_V16_LO   ((size_t)27262976)
// V^T hi/lo (overlays xn hi/lo, dead after qkv GEMM)
#define F_VT_HI    ((size_t)12582912)
#define F_VT_LO    ((size_t)14680064)
#define F_AO_HI    ((size_t)29360128)
#define F_AO_LO    ((size_t)31457280)
#define F_XF_HI    ((size_t)33554432)
#define F_XF_LO    ((size_t)35651584)
#define F_WQKV_HI  ((size_t)37748736)
#define F_WQKV_LO  ((size_t)39321600)
#define F_WAIN_HI  ((size_t)40894464)
#define F_WAIN_LO  ((size_t)42467328)
#define F_WAOUT_HI ((size_t)44040192)
#define F_WAOUT_LO ((size_t)44564480)
#define F_WR1_HI   ((size_t)45088768)
#define F_WR1_LO   ((size_t)47185920)
// phase3 overlay (phase1/2 contents dead)
#define F_EXPIN    ((size_t)16777216)
#define F_MLP1T    ((size_t)22020096)
#define F_MID      ((size_t)30408704)
#define F_MLP2T    ((size_t)35651584)
// persistent
#define F_X1       ((size_t)49283072)
#define F_XF       ((size_t)53477376)
#define F_PROBS    ((size_t)57671680)
#define F_INDS     ((size_t)57679872)
#define F_KEEP     ((size_t)57688064)
#define F_FLAT     ((size_t)57696256)

__device__ __forceinline__ ushort f2h(float f) {
    _Float16 h = (_Float16)f;
    union { _Float16 h; ushort u; } c; c.h = h; return c.u;
}
__device__ __forceinline__ float h2f(ushort u) {
    union { ushort u; _Float16 h; } c; c.u = u; return (float)c.h;
}
__device__ __forceinline__ float gelu_exact(float x) {
    return 0.5f * x * (1.0f + erff(x * 0.7071067811865475f));
}

// async global->LDS, 16B per lane; lds dest = base + lane*16 (wave-uniform base)
__device__ __forceinline__ void gl16(const void* g, void* l) {
    __builtin_amdgcn_global_load_lds(
        (const __attribute__((address_space(1))) void*)g,
        (__attribute__((address_space(3))) void*)l, 16, 0, 0);
}

// ---------------- split fp32 -> (hi fp16, lo fp16 scaled by 2048) ----------------
__global__ __launch_bounds__(256) void split_f32(const float* __restrict__ x,
                                                 ushort* __restrict__ hi,
                                                 ushort* __restrict__ lo, int n4) {
    int i = blockIdx.x * 256 + threadIdx.x;
    if (i >= n4) return;
    float4 v = ((const float4*)x)[i];
    float vv[4] = {v.x, v.y, v.z, v.w};
    ushort h[4], l[4];
#pragma unroll
    for (int e = 0; e < 4; e++) {
        h[e] = f2h(vv[e]);
        l[e] = f2h((vv[e] - h2f(h[e])) * LSCALE);
    }
    ((ushort4*)hi)[i] = make_ushort4(h[0], h[1], h[2], h[3]);
    ((ushort4*)lo)[i] = make_ushort4(l[0], l[1], l[2], l[3]);
}

// ---------------- LayerNorm: optional fp32 / fp16-hi / fp16-lo outputs ----------------
__global__ __launch_bounds__(256) void ln_kernel(const float* __restrict__ x,
                                                 const float* __restrict__ g,
                                                 const float* __restrict__ b,
                                                 float* __restrict__ yf,
                                                 ushort* __restrict__ yhi,
                                                 ushort* __restrict__ ylo) {
    __shared__ float red0[4], red1[4], bc[2];
    const size_t t = blockIdx.x;
    const float* row = x + t * DIM;
    float v[4];
    float s = 0.f, s2 = 0.f;
#pragma unroll
    for (int i = 0; i < 4; i++) {
        float vv = row[threadIdx.x + i * 256];
        v[i] = vv; s += vv; s2 += vv * vv;
    }
#pragma unroll
    for (int off = 32; off > 0; off >>= 1) {
        s  += __shfl_down(s, off);
        s2 += __shfl_down(s2, off);
    }
    const int lane = threadIdx.x & 63, wid = threadIdx.x >> 6;
    if (lane == 0) { red0[wid] = s; red1[wid] = s2; }
    __syncthreads();
    if (threadIdx.x == 0) {
        float S = red0[0] + red0[1] + red0[2] + red0[3];
        float S2 = red1[0] + red1[1] + red1[2] + red1[3];
        float mean = S * (1.0f / DIM);
        float var = S2 * (1.0f / DIM) - mean * mean;
        bc[0] = mean; bc[1] = rsqrtf(var + 1e-5f);
    }
    __syncthreads();
    const float mean = bc[0], r = bc[1];
#pragma unroll
    for (int i = 0; i < 4; i++) {
        int idx = threadIdx.x + i * 256;
        float val = (v[i] - mean) * r * g[idx] + b[idx];
        size_t o = t * DIM + idx;
        if (yf) yf[o] = val;
        if (yhi) {
            ushort h = f2h(val);
            yhi[o] = h;
            if (ylo) ylo[o] = f2h((val - h2f(h)) * LSCALE);
        }
    }
}

// ---------------- fp16 MFMA NT GEMM; SPLIT = scaled hi/lo (fp32-accurate) ----------------
// Staging: global_load_lds (16B/lane DMA) into linear [128][32] LDS tiles.
// Bank-conflict fix (rule 21): chunk_phys = chunk_log ^ ((row>>1)&3); inverse applied
// on per-lane global source, forward applied on fragment reads -> 2-way (free).
template<bool SPLIT>
__global__ __launch_bounds__(256) void gemm_ht(
    const ushort* __restrict__ Ahi, const ushort* __restrict__ Alo, int lda, long long sA,
    const ushort* __restrict__ Bhi, const ushort* __restrict__ Blo, int ldb, long long sB,
    const float* __restrict__ bias, long long sBias,
    const float* __restrict__ resid, int ldr,
    float* __restrict__ outf, ushort* __restrict__ outhi, ushort* __restrict__ outlo,
    int ldc, long long sC, int Kdim, int act, int accum) {
    __shared__ ushort sAh[128][32];
    __shared__ ushort sBh[128][32];
    __shared__ ushort sAl[SPLIT ? 128 : 1][32];
    __shared__ ushort sBl[SPLIT ? 128 : 1][32];
    const int z = blockIdx.z;
    Ahi += (size_t)z * sA; Bhi += (size_t)z * sB;
    if constexpr (SPLIT) { Alo += (size_t)z * sA; Blo += (size_t)z * sB; }
    if (bias) bias += (size_t)z * sBias;
    if (outf) outf += (size_t)z * sC;
    if (outhi) outhi += (size_t)z * sC;
    if (outlo) outlo += (size_t)z * sC;

    const int tid = threadIdx.x;
    const int row0 = blockIdx.y * 128, col0 = blockIdx.x * 128;
    const int lane = tid & 63;
    const int m = lane & 15, half = lane >> 4;
    const int w = tid >> 6;
    const int ar0 = (w >> 1) * 64, bc0 = (w & 1) * 64;

    // staging geometry: wave w covers rows [w*32, w*32+32); lane l -> row w*32+(l>>2),
    // phys chunk l&3. Source pre-swizzle: logical chunk = (l&3) ^ ((row>>1)&3) = (l&3)^((l>>3)&3).
    const int srow = w * 32 + (lane >> 2);                 // round-0 row (round-1 = +16)
    const int ssw  = (((lane >> 3) & 3) ^ (lane & 3)) * 8; // ushort offset of logical chunk
    // fragment-read swizzle: chunk = half ^ ((fragrow>>1)&3) = half ^ ((m>>1)&3)
    const int rsw8 = ((((m >> 1) & 3) ^ half)) * 8;

    floatx4 acc[4][4];
    floatx4 acc2[SPLIT ? 4 : 1][SPLIT ? 4 : 1];
#pragma unroll
    for (int i = 0; i < 4; i++)
#pragma unroll
        for (int j = 0; j < 4; j++) acc[i][j] = (floatx4){0.f, 0.f, 0.f, 0.f};
    if constexpr (SPLIT) {
#pragma unroll
        for (int i = 0; i < 4; i++)
#pragma unroll
            for (int j = 0; j < 4; j++) acc2[i][j] = (floatx4){0.f, 0.f, 0.f, 0.f};
    }

    for (int k0 = 0; k0 < Kdim; k0 += 32) {
        __syncthreads();   // previous tile fully consumed before DMA overwrite
        {
            const ushort* gA = Ahi + (size_t)(row0 + srow) * lda + k0 + ssw;
            const ushort* gB = Bhi + (size_t)(col0 + srow) * ldb + k0 + ssw;
            gl16(gA,                      &sAh[w * 32][0]);
            gl16(gA + (size_t)16 * lda,   &sAh[w * 32 + 16][0]);
            gl16(gB,                      &sBh[w * 32][0]);
            gl16(gB + (size_t)16 * ldb,   &sBh[w * 32 + 16][0]);
            if constexpr (SPLIT) {
                const ushort* gAl = Alo + (size_t)(row0 + srow) * lda + k0 + ssw;
                const ushort* gBl = Blo + (size_t)(col0 + srow) * ldb + k0 + ssw;
                gl16(gAl,                    &sAl[w * 32][0]);
                gl16(gAl + (size_t)16 * lda, &sAl[w * 32 + 16][0]);
                gl16(gBl,                    &sBl[w * 32][0]);
                gl16(gBl + (size_t)16 * ldb, &sBl[w * 32 + 16][0]);
            }
        }
        __syncthreads();   // compiler-emitted vmcnt(0) drain: tile ready
        half8 fa[4], fb[4], fal[4], fbl[4];
#pragma unroll
        for (int i = 0; i < 4; i++) fa[i] = *(const half8*)&sAh[ar0 + i * 16 + m][rsw8];
#pragma unroll
        for (int j = 0; j < 4; j++) fb[j] = *(const half8*)&sBh[bc0 + j * 16 + m][rsw8];
        if constexpr (SPLIT) {
#pragma unroll
            for (int i = 0; i < 4; i++) fal[i] = *(const half8*)&sAl[ar0 + i * 16 + m][rsw8];
#pragma unroll
            for (int j = 0; j < 4; j++) fbl[j] = *(const half8*)&sBl[bc0 + j * 16 + m][rsw8];
        }
#pragma unroll
        for (int i = 0; i < 4; i++)
#pragma unroll
            for (int j = 0; j < 4; j++) {
                acc[i][j] = __builtin_amdgcn_mfma_f32_16x16x32_f16(fa[i], fb[j], acc[i][j], 0, 0, 0);
                if constexpr (SPLIT) {
                    acc2[i][j] = __builtin_amdgcn_mfma_f32_16x16x32_f16(fa[i], fbl[j], acc2[i][j], 0, 0, 0);
                    acc2[i][j] = __builtin_amdgcn_mfma_f32_16x16x32_f16(fal[i], fb[j], acc2[i][j], 0, 0, 0);
                }
            }
    }
    // epilogue: C/D layout col=lane&15, row=(lane>>4)*4+reg
#pragma unroll
    for (int i = 0; i < 4; i++) {
#pragma unroll
        for (int j = 0; j < 4; j++) {
            const int col = col0 + bc0 + j * 16 + m;
            const float bv = bias ? bias[col] : 0.f;
#pragma unroll
            for (int r = 0; r < 4; r++) {
                const int row = row0 + ar0 + i * 16 + half * 4 + r;
                float v = acc[i][j][r];
                if constexpr (SPLIT) v += acc2[i][j][r] * INV_LSCALE;
                v += bv;
                if (resid) v += resid[(size_t)row * ldr + col];
                if (accum) v += outf[(size_t)row * ldc + col];
                if (act) v = gelu_exact(v);
                const size_t o = (size_t)row * ldc + col;
                if (outf) outf[o] = v;
                if (outhi) {
                    ushort h = f2h(v);
                    outhi[o] = h;
                    if (outlo) outlo[o] = f2h((v - h2f(h)) * LSCALE);
                }
            }
        }
    }
}

// ---------------- transpose fp32 [R,C] -> fp16 [C,R], batched ----------------
__global__ __launch_bounds__(256) void transpose_h(const float* __restrict__ in, long long sIn, int ldin,
                                                   ushort* __restrict__ out, long long sOut, int ldout) {
    __shared__ float t[32][33];
    const int z = blockIdx.z;
    in += (size_t)z * sIn; out += (size_t)z * sOut;
    const int cx = threadIdx.x & 31, ry = threadIdx.x >> 5;
    const int r0 = blockIdx.y * 32, c0 = blockIdx.x * 32;
#pragma unroll
    for (int rr = 0; rr < 4; rr++)
        t[ry + rr * 8][cx] = in[(size_t)(r0 + ry + rr * 8) * ldin + c0 + cx];
    __syncthreads();
#pragma unroll
    for (int rr = 0; rr < 4; rr++)
        out[(size_t)(c0 + ry + rr * 8) * ldout + r0 + cx] = f2h(t[cx][ry + rr * 8]);
}

// ---------------- V^T builder: v_hi/v_lo [4096][1024] -> vT [64 bh][64 d][1024 s] ----------------
__global__ __launch_bounds__(256) void vtrans_kernel(const ushort* __restrict__ vhi,
                                                     const ushort* __restrict__ vlo,
                                                     ushort* __restrict__ vthi,
                                                     ushort* __restrict__ vtlo) {
    __shared__ ushort th[32][72], tl[32][72];
    const int bh = blockIdx.y, b = bh >> 4, h = bh & 15;
    const int s0 = blockIdx.x * 32;
    const int t = threadIdx.x;
    {
        const int s = t >> 3, d0 = (t & 7) * 8;
        const size_t src = ((size_t)(b * 1024 + s0 + s)) * 1024 + h * 64 + d0;
        *(uint4*)&th[s][d0] = *(const uint4*)&vhi[src];
        *(uint4*)&tl[s][d0] = *(const uint4*)&vlo[src];
    }
    __syncthreads();
    {
        const int d = t >> 2, soff = (t & 3) * 8;
        us8 rh, rl;
#pragma unroll
        for (int e = 0; e < 8; e++) { rh[e] = th[soff + e][d]; rl[e] = tl[soff + e][d]; }
        const size_t dst = (size_t)bh * 65536 + (size_t)d * 1024 + s0 + soff;
        *(us8*)&vthi[dst] = rh;
        *(us8*)&vtlo[dst] = rl;
    }
}

// ---------------- causal flash attention, split fp16 MFMA (fp32-accurate) ----------------
// 128 q-rows/block, 4 waves x 32 rows, K-tiles of 64. Q/K/V^T fragments loaded
// direct from global in MFMA layout; P goes through wave-private swizzled LDS.
__global__ __launch_bounds__(256, 2) void attn_mfma(
        const ushort* __restrict__ qh_, const ushort* __restrict__ ql_,
        const ushort* __restrict__ kh_, const ushort* __restrict__ kl_,
        const ushort* __restrict__ vth_, const ushort* __restrict__ vtl_,
        ushort* __restrict__ ao_hi, ushort* __restrict__ ao_lo) {
    __shared__ ushort plds[4][2][2048];   // [wave][hi/lo][32 rows x 64 cols, xor-swizzled]
    const int bh = blockIdx.y;
    const int b = bh >> 4;
    const int qt = 7 - blockIdx.x;        // high-work tiles dispatch first
    const int tid = threadIdx.x;
    const int w = tid >> 6, lane = tid & 63;
    const int m = lane & 15, hq = lane >> 4;
    const int wrow = qt * 128 + w * 32;   // global q-row base of this wave (within b)
    const size_t cbase = ((size_t)b * 1024) * 1024 + (size_t)(bh & 15) * 64;
    const size_t vtbase = (size_t)bh * 65536;

    // Q fragments (persistent): lane holds Q[wrow+i*16+m][kk*32+hq*8 ..+7]
    half8 qfh[2][2], qfl[2][2];
#pragma unroll
    for (int i = 0; i < 2; i++)
#pragma unroll
        for (int kk = 0; kk < 2; kk++) {
            const size_t o = cbase + (size_t)(wrow + i * 16 + m) * 1024 + kk * 32 + hq * 8;
            qfh[i][kk] = *(const half8*)&qh_[o];
            qfl[i][kk] = *(const half8*)&ql_[o];
        }

    floatx4 accO[2][4], accO2[2][4];
#pragma unroll
    for (int i = 0; i < 2; i++)
#pragma unroll
        for (int d = 0; d < 4; d++) {
            accO[i][d] = (floatx4){0.f, 0.f, 0.f, 0.f};
            accO2[i][d] = (floatx4){0.f, 0.f, 0.f, 0.f};
        }
    float mx[2][4], ls[2][4];
#pragma unroll
    for (int i = 0; i < 2; i++)
#pragma unroll
        for (int r = 0; r < 4; r++) { mx[i][r] = -3.0e38f; ls[i][r] = 0.f; }

    const int ntiles = (wrow + 31) / 64 + 1;   // per-wave causal tile count (no barriers)
    for (int t = 0; t < ntiles; t++) {
        const int j0 = t * 64;
        // ---- QK^T: S = Qh*Kh + (Qh*Kl + Ql*Kh)/2048 ----
        floatx4 accS[2][4], accS2[2][4];
#pragma unroll
        for (int i = 0; i < 2; i++)
#pragma unroll
            for (int jf = 0; jf < 4; jf++) {
                accS[i][jf] = (floatx4){0.f, 0.f, 0.f, 0.f};
                accS2[i][jf] = (floatx4){0.f, 0.f, 0.f, 0.f};
            }
#pragma unroll
        for (int kk = 0; kk < 2; kk++) {
            half8 kfh[4], kfl[4];
#pragma unroll
            for (int jf = 0; jf < 4; jf++) {
                const size_t o = cbase + (size_t)(j0 + jf * 16 + m) * 1024 + kk * 32 + hq * 8;
                kfh[jf] = *(const half8*)&kh_[o];
                kfl[jf] = *(const half8*)&kl_[o];
            }
#pragma unroll
            for (int i = 0; i < 2; i++)
#pragma unroll
                for (int jf = 0; jf < 4; jf++) {
                    accS[i][jf] = __builtin_amdgcn_mfma_f32_16x16x32_f16(qfh[i][kk], kfh[jf], accS[i][jf], 0, 0, 0);
                    accS2[i][jf] = __builtin_amdgcn_mfma_f32_16x16x32_f16(qfh[i][kk], kfl[jf], accS2[i][jf], 0, 0, 0);
                    accS2[i][jf] = __builtin_amdgcn_mfma_f32_16x16x32_f16(qfl[i][kk], kfh[jf], accS2[i][jf], 0, 0, 0);
                }
        }
        // ---- combine, scale, causal mask ----
        const bool diag = (j0 + 63 > wrow);
        float p[2][4][4];
#pragma unroll
        for (int i = 0; i < 2; i++)
#pragma unroll
            for (int jf = 0; jf < 4; jf++)
#pragma unroll
                for (int r = 0; r < 4; r++) {
                    float s = (accS[i][jf][r] + accS2[i][jf][r] * INV_LSCALE) * 0.125f;
                    if (diag && (j0 + jf * 16 + m > wrow + i * 16 + hq * 4 + r)) s = -3.0e38f;
                    p[i][jf][r] = s;
                }
        // ---- online softmax per row; rows live in the same (hq,r) lanes as O ----
#pragma unroll
        for (int i = 0; i < 2; i++)
#pragma unroll
            for (int r = 0; r < 4; r++) {
                float tm = fmaxf(fmaxf(p[i][0][r], p[i][1][r]), fmaxf(p[i][2][r], p[i][3][r]));
#pragma unroll
                for (int off = 8; off > 0; off >>= 1) tm = fmaxf(tm, __shfl_xor(tm, off));
                const float mn = fmaxf(mx[i][r], tm);
                const float c = __expf(mx[i][r] - mn);
                mx[i][r] = mn;
                float rs = 0.f;
#pragma unroll
                for (int jf = 0; jf < 4; jf++) {
                    const float e = __expf(p[i][jf][r] - mn);
                    p[i][jf][r] = e;
                    rs += e;
                }
#pragma unroll
                for (int off = 8; off > 0; off >>= 1) rs += __shfl_xor(rs, off);
                ls[i][r] = ls[i][r] * c + rs;
#pragma unroll
                for (int d = 0; d < 4; d++) { accO[i][d][r] *= c; accO2[i][d][r] *= c; }
            }
        // ---- P -> LDS (hi/lo, xor-swizzled rows) ----
#pragma unroll
        for (int i = 0; i < 2; i++)
#pragma unroll
            for (int jf = 0; jf < 4; jf++)
#pragma unroll
                for (int r = 0; r < 4; r++) {
                    const int row = i * 16 + hq * 4 + r;
                    const int idx = row * 64 + ((jf * 16 + m) ^ ((row & 7) << 3));
                    const float pv = p[i][jf][r];
                    const ushort hh = f2h(pv);
                    plds[w][0][idx] = hh;
                    plds[w][1][idx] = f2h((pv - h2f(hh)) * LSCALE);
                }
        // ---- PV: O += Ph*Vh + (Ph*Vl + Pl*Vh)/2048 ----
#pragma unroll
        for (int kk = 0; kk < 2; kk++) {
            half8 pfh[2], pfl[2], vfh[4], vfl[4];
#pragma unroll
            for (int i = 0; i < 2; i++) {
                const int row = i * 16 + m;
                const int idx = row * 64 + ((kk * 32 + hq * 8) ^ ((row & 7) << 3));
                pfh[i] = *(const half8*)&plds[w][0][idx];
                pfl[i] = *(const half8*)&plds[w][1][idx];
            }
#pragma unroll
            for (int d = 0; d < 4; d++) {
                const size_t o = vtbase + (size_t)(d * 16 + m) * 1024 + j0 + kk * 32 + hq * 8;
                vfh[d] = *(const half8*)&vth_[o];
                vfl[d] = *(const half8*)&vtl_[o];
            }
#pragma unroll
            for (int i = 0; i < 2; i++)
#pragma unroll
                for (int d = 0; d < 4; d++) {
                    accO[i][d] = __builtin_amdgcn_mfma_f32_16x16x32_f16(pfh[i], vfh[d], accO[i][d], 0, 0, 0);
                    accO2[i][d] = __builtin_amdgcn_mfma_f32_16x16x32_f16(pfh[i], vfl[d], accO2[i][d], 0, 0, 0);
                    accO2[i][d] = __builtin_amdgcn_mfma_f32_16x16x32_f16(pfl[i], vfh[d], accO2[i][d], 0, 0, 0);
                }
        }
    }
    // ---- epilogue: normalize + write hi/lo ----
#pragma unroll
    for (int i = 0; i < 2; i++)
#pragma unroll
        for (int r = 0; r < 4; r++) {
            const float inv = 1.f / ls[i][r];
            const size_t rb = cbase + (size_t)(wrow + i * 16 + hq * 4 + r) * 1024;
#pragma unroll
            for (int d = 0; d < 4; d++) {
                const float v = (accO[i][d][r] + accO2[i][d][r] * INV_LSCALE) * inv;
                const ushort hh = f2h(v);
                const size_t o = rb + d * 16 + m;
                ao_hi[o] = hh;
                ao_lo[o] = f2h((v - h2f(hh)) * LSCALE);
            }
        }
}

// ---------------- router second GEMM + top-2 + softmax probs (pure fp32) ----------------
__global__ __launch_bounds__(256) void router2_kernel(const float* __restrict__ h1,
                                                      const float* __restrict__ w2,
                                                      const float* __restrict__ b2,
                                                      float* __restrict__ logits_out,
                                                      float* __restrict__ probs,
                                                      int* __restrict__ inds) {
    __shared__ float red[16][4];
    __shared__ float lg[16];
    const int t = blockIdx.x;
    const float* hrow = h1 + (size_t)t * HMLP;
    float acc[16];
#pragma unroll
    for (int m = 0; m < 16; m++) acc[m] = 0.f;
    for (int i = 0; i < 16; i++) {
        int kk = threadIdx.x + i * 256;
        float hv = hrow[kk];
#pragma unroll
        for (int m = 0; m < 16; m++) acc[m] = fmaf(hv, w2[m * HMLP + kk], acc[m]);
    }
#pragma unroll
    for (int m = 0; m < 16; m++)
#pragma unroll
        for (int off = 32; off > 0; off >>= 1) acc[m] += __shfl_down(acc[m], off);
    const int lane = threadIdx.x & 63, wid = threadIdx.x >> 6;
    if (lane == 0) {
#pragma unroll
        for (int m = 0; m < 16; m++) red[m][wid] = acc[m];
    }
    __syncthreads();
    if (threadIdx.x < 16) {
        float v = red[threadIdx.x][0] + red[threadIdx.x][1] + red[threadIdx.x][2] + red[threadIdx.x][3]
                  + b2[threadIdx.x];
        lg[threadIdx.x] = v;
        logits_out[(size_t)t * 16 + threadIdx.x] = v;
    }
    __syncthreads();
    if (threadIdx.x == 0) {
        int i0 = 0; float v0 = lg[0];
        for (int m = 1; m < 16; m++) if (lg[m] > v0) { v0 = lg[m]; i0 = m; }
        int i1 = -1; float v1 = -3.4e38f;
        for (int m = 0; m < 16; m++) if (m != i0 && lg[m] > v1) { v1 = lg[m]; i1 = m; }
        float e1 = expf(v1 - v0);
        float den = 1.f + e1;
        inds[2 * t] = i0; inds[2 * t + 1] = i1;
        probs[2 * t] = 1.f / den; probs[2 * t + 1] = e1 / den;
    }
}

// ---------------- capacity scan ----------------
__global__ __launch_bounds__(256) void scan_kernel(const int* __restrict__ inds,
                                                   int* __restrict__ keep,
                                                   int* __restrict__ flat) {
    __shared__ int counts[256][16];
    const int t = threadIdx.x;
#pragma unroll
    for (int e = 0; e < 16; e++) counts[t][e] = 0;
    const int base = t * 32;
    for (int i = 0; i < 32; i++) counts[t][inds[base + i]]++;
    __syncthreads();
    if (t < 16) {
        int run = 0;
        for (int c = 0; c < 256; c++) { int tmp = counts[c][t]; counts[c][t] = run; run += tmp; }
    }
    __syncthreads();
    for (int i = 0; i < 32; i++) {
        int e = inds[base + i];
        int p = counts[t][e]++;
        keep[base + i] = (p < CAP) ? 1 : 0;
        flat[base + i] = e * CAP + p;
    }
}

// ---------------- scatter tokens (fp32 xf -> fp16 expert_in) ----------------
__global__ __launch_bounds__(256) void scatter_kernel(const float* __restrict__ xf,
                                                      const int* __restrict__ keep,
                                                      const int* __restrict__ flat,
                                                      ushort* __restrict__ expert_in) {
    const int e = blockIdx.x;
    if (!keep[e]) return;
    const int token = e >> 1;
    const float* src = xf + (size_t)token * DIM;
    ushort* dst = expert_in + (size_t)flat[e] * DIM;
#pragma unroll
    for (int i = 0; i < 4; i++) dst[threadIdx.x + i * 256] = f2h(src[threadIdx.x + i * 256]);
}

// ---------------- combine ----------------
__global__ __launch_bounds__(256) void combine_kernel(const float* __restrict__ x1,
                                                      const float* __restrict__ xf,
                                                      const float* __restrict__ eout,
                                                      const float* __restrict__ probs,
                                                      const int* __restrict__ keep,
                                                      const int* __restrict__ flat,
                                                      float* __restrict__ out) {
    const int t = blockIdx.x;
    const int k0 = keep[2 * t], k1 = keep[2 * t + 1];
    const float p0 = probs[2 * t], p1 = probs[2 * t + 1];
    const size_t f0 = (size_t)flat[2 * t] * DIM, f1 = (size_t)flat[2 * t + 1] * DIM;
    const bool has = (k0 || k1);
    const size_t base = (size_t)t * DIM;
#pragma unroll
    for (int i = 0; i < 4; i++) {
        const int idx = threadIdx.x + i * 256;
        float mo;
        if (has) {
            mo = 0.f;
            if (k0) mo += p0 * eout[f0 + idx];
            if (k1) mo += p1 * eout[f1 + idx];
        } else {
            mo = xf[base + idx];
        }
        out[base + idx] = x1[base + idx] + mo;
    }
}

extern "C" void kernel_launch(void* const* d_in, const int* in_sizes, int n_in,
                              void* d_out, int out_size, void* d_ws, size_t ws_size,
                              hipStream_t stream) {
    const float* x          = (const float*)d_in[0];
    const float* ln1_g      = (const float*)d_in[1];
    const float* ln1_b      = (const float*)d_in[2];
    const float* qkv_w      = (const float*)d_in[3];
    const float* qkv_b      = (const float*)d_in[4];
    const float* attn_in_w  = (const float*)d_in[5];
    const float* attn_in_b  = (const float*)d_in[6];
    const float* attn_out_w = (const float*)d_in[7];
    const float* attn_out_b = (const float*)d_in[8];
    const float* ln2_g      = (const float*)d_in[9];
    const float* ln2_b      = (const float*)d_in[10];
    const float* r_w1       = (const float*)d_in[11];
    const float* r_b1       = (const float*)d_in[12];
    const float* r_w2       = (const float*)d_in[13];
    const float* r_b2       = (const float*)d_in[14];
    const float* mlp1       = (const float*)d_in[15];
    const float* mlp2       = (const float*)d_in[16];

    float* ws = (float*)d_ws;
    ushort* qkv_hi   = (ushort*)(ws + F_QKV_HI);
    ushort* qkv_lo   = (ushort*)(ws + F_QKV_LO);
    ushort* xn_hi    = (ushort*)(ws + F_XN_HI);
    ushort* xn_lo    = (ushort*)(ws + F_XN_LO);
    float*  h1       = ws + F_H1;
    float*  eout     = ws + F_EOUT;
    ushort* q_hi     = (ushort*)(ws + F_Q16_HI);
    ushort* q_lo     = (ushort*)(ws + F_Q16_LO);
    ushort* v_hi     = (ushort*)(ws + F_V16_HI);
    ushort* v_lo     = (ushort*)(ws + F_V16_LO);
    ushort* k_hi     = (ushort*)(ws + F_K16_HI);
    ushort* k_lo     = (ushort*)(ws + F_K16_LO);
    ushort* vt_hi    = (ushort*)(ws + F_VT_HI);
    ushort* vt_lo    = (ushort*)(ws + F_VT_LO);
    ushort* ao_hi    = (ushort*)(ws + F_AO_HI);
    ushort* ao_lo    = (ushort*)(ws + F_AO_LO);
    ushort* xf_hi    = (ushort*)(ws + F_XF_HI);
    ushort* xf_lo    = (ushort*)(ws + F_XF_LO);
    ushort* wqkv_hi  = (ushort*)(ws + F_WQKV_HI);
    ushort* wqkv_lo  = (ushort*)(ws + F_WQKV_LO);
    ushort* wain_hi  = (ushort*)(ws + F_WAIN_HI);
    ushort* wain_lo  = (ushort*)(ws + F_WAIN_LO);
    ushort* waout_hi = (ushort*)(ws + F_WAOUT_HI);
    ushort* waout_lo = (ushort*)(ws + F_WAOUT_LO);
    ushort* wr1_hi   = (ushort*)(ws + F_WR1_HI);
    ushort* wr1_lo   = (ushort*)(ws + F_WR1_LO);
    ushort* expert_in= (ushort*)(ws + F_EXPIN);
    ushort* mlp1t    = (ushort*)(ws + F_MLP1T);
    ushort* mid      = (ushort*)(ws + F_MID);
    ushort* mlp2t    = (ushort*)(ws + F_MLP2T);
    float*  x1       = ws + F_X1;
    float*  xf       = ws + F_XF;
    float*  probs    = ws + F_PROBS;
    int*    inds     = (int*)(ws + F_INDS);
    int*    keep     = (int*)(ws + F_KEEP);
    int*    flat     = (int*)(ws + F_FLAT);

    float* out        = (float*)d_out;
    float* logits_out = out + (size_t)NTOK * DIM;

    // weight splits (fp16 hi + scaled lo)
    split_f32<<<(3145728 / 4 + 255) / 256, 256, 0, stream>>>(qkv_w, wqkv_hi, wqkv_lo, 3145728 / 4);
    split_f32<<<(3145728 / 4 + 255) / 256, 256, 0, stream>>>(attn_in_w, wain_hi, wain_lo, 3145728 / 4);
    split_f32<<<(1048576 / 4 + 255) / 256, 256, 0, stream>>>(attn_out_w, waout_hi, waout_lo, 1048576 / 4);
    split_f32<<<(4194304 / 4 + 255) / 256, 256, 0, stream>>>(r_w1, wr1_hi, wr1_lo, 4194304 / 4);

    // 1. LN1 -> xn hi/lo
    ln_kernel<<<NTOK, 256, 0, stream>>>(x, ln1_g, ln1_b, nullptr, xn_hi, xn_lo);
    // 2. qkv = xn @ qkv_w.T + qkv_b   (split, out hi/lo)
    gemm_ht<true><<<dim3(H3 / 128, NTOK / 128, 1), 256, 0, stream>>>(
        xn_hi, xn_lo, DIM, 0, wqkv_hi, wqkv_lo, DIM, 0, qkv_b, 0,
        nullptr, 0, nullptr, qkv_hi, qkv_lo, H3, 0, DIM, 0, 0);
    // 3. q/k/v in-projections, batched z=3 (split, out fp16 hi/lo directly)
    gemm_ht<true><<<dim3(DIM / 128, NTOK / 128, 3), 256, 0, stream>>>(
        qkv_hi, qkv_lo, H3, 1024, wain_hi, wain_lo, DIM, 1048576, attn_in_b, 1024,
        nullptr, 0, nullptr, q_hi, q_lo, DIM, 4194304, DIM, 0, 0);
    // 3b. build V^T hi/lo per (b,h) for the PV B-operand
    vtrans_kernel<<<dim3(32, 64), 256, 0, stream>>>(v_hi, v_lo, vt_hi, vt_lo);
    // 4. MFMA flash attention -> ao hi/lo
    attn_mfma<<<dim3(8, 64), 256, 0, stream>>>(q_hi, q_lo, k_hi, k_lo, vt_hi, vt_lo, ao_hi, ao_lo);
    // 5. x1 = x + ao @ attn_out_w.T + b  (split, out fp32)
    gemm_ht<true><<<dim3(DIM / 128, NTOK / 128, 1), 256, 0, stream>>>(
        ao_hi, ao_lo, DIM, 0, waout_hi, waout_lo, DIM, 0, attn_out_b, 0,
        x, DIM, x1, nullptr, nullptr, DIM, 0, DIM, 0, 0);
    // 6. LN2 -> xf fp32 + hi/lo
    ln_kernel<<<NTOK, 256, 0, stream>>>(x1, ln2_g, ln2_b, xf, xf_hi, xf_lo);
    // 7. h1 = gelu(xf @ r_w1.T + r_b1)  (split, out fp32)
    gemm_ht<true><<<dim3(HMLP / 128, NTOK / 128, 1), 256, 0, stream>>>(
        xf_hi, xf_lo, DIM, 0, wr1_hi, wr1_lo, DIM, 0, r_b1, 0,
        nullptr, 0, h1, nullptr, nullptr, HMLP, 0, DIM, 1, 0);
    // 8. router logits + top-2 (fp32)
    router2_kernel<<<NTOK, 256, 0, stream>>>(h1, r_w2, r_b2, logits_out, probs, inds);
    // 9. capacity scan
    scan_kernel<<<1, 256, 0, stream>>>(inds, keep, flat);
    // 10. scatter (fp32 xf -> fp16 expert buffers)
    scatter_kernel<<<NTOK * 2, 256, 0, stream>>>(xf, keep, flat, expert_in);
    // 11. expert FFN, fp16 MFMA, H chunked (transpose weights per chunk)
    for (int c = 0; c < HMLP / HCHUNK; c++) {
        transpose_h<<<dim3(32, 32, NEXP), 256, 0, stream>>>(
            mlp1 + (size_t)c * HCHUNK, (long long)DIM * HMLP, HMLP, mlp1t, 1048576, DIM);
        gemm_ht<false><<<dim3(HCHUNK / 128, CAP / 128, NEXP), 256, 0, stream>>>(
            expert_in, nullptr, DIM, 655360, mlp1t, nullptr, DIM, 1048576, nullptr, 0,
            nullptr, 0, nullptr, mid, nullptr, HCHUNK, 655360, DIM, 1, 0);
        transpose_h<<<dim3(32, 32, NEXP), 256, 0, stream>>>(
            mlp2 + (size_t)c * HCHUNK * DIM, (long long)HMLP * DIM, DIM, mlp2t, 1048576, HCHUNK);
        gemm_ht<false><<<dim3(DIM / 128, CAP / 128, NEXP), 256, 0, stream>>>(
            mid, nullptr, HCHUNK, 655360, mlp2t, nullptr, HCHUNK, 1048576, nullptr, 0,
            nullptr, 0, eout, nullptr, nullptr, DIM, 655360, HCHUNK, 0, c > 0);
    }
    // 12. combine + residual
    combine_kernel<<<NTOK, 256, 0, stream>>>(x1, xf, eout, probs, keep, flat, out);
}

// Round 5
// 2127.449 us; speedup vs baseline: 1.2984x; 1.0733x over previous
//
#include <hip/hip_runtime.h>
#include <math.h>

#define NTOK   4096
#define DIM    1024
#define H3     3072
#define HMLP   4096
#define NEXP   16
#define CAP    640
#define HCHUNK 1024
#define LSCALE 2048.0f
#define INV_LSCALE (1.0f / 2048.0f)

typedef _Float16 half8 __attribute__((ext_vector_type(8)));
typedef __attribute__((ext_vector_type(4))) float floatx4;
typedef __attribute__((ext_vector_type(8))) ushort us8;

// ---- workspace layout (float-element offsets) ----
#define F_QKV_HI   ((size_t)0)
#define F_QKV_LO   ((size_t)6291456)
#define F_XN_HI    ((size_t)12582912)
#define F_XN_LO    ((size_t)14680064)
#define F_H1       ((size_t)0)
#define F_EOUT     ((size_t)0)
// q/k/v fp16 hi/lo (overlays old fp32 qbuf/kbuf/vbuf region 16777216..29360128)
#define F_Q16_HI   ((size_t)16777216)
#define F_K16_HI   ((size_t)18874368)
#define F_V16_HI   ((size_t)20971520)
#define F_Q16_LO   ((size_t)23068672)
#define F_K16_LO   ((size_t)25165824)
#define F_V16_LO   ((size_t)27262976)
// V^T hi/lo (overlays xn hi/lo, dead after qkv GEMM)
#define F_VT_HI    ((size_t)12582912)
#define F_VT_LO    ((size_t)14680064)
#define F_AO_HI    ((size_t)29360128)
#define F_AO_LO    ((size_t)31457280)
#define F_XF_HI    ((size_t)33554432)
#define F_XF_LO    ((size_t)35651584)
#define F_WQKV_HI  ((size_t)37748736)
#define F_WQKV_LO  ((size_t)39321600)
#define F_WAIN_HI  ((size_t)40894464)
#define F_WAIN_LO  ((size_t)42467328)
#define F_WAOUT_HI ((size_t)44040192)
#define F_WAOUT_LO ((size_t)44564480)
#define F_WR1_HI   ((size_t)45088768)
#define F_WR1_LO   ((size_t)47185920)
// phase3 overlay (phase1/2 contents dead)
#define F_EXPIN    ((size_t)16777216)
#define F_MLP1T    ((size_t)22020096)
#define F_MID      ((size_t)30408704)
#define F_MLP2T    ((size_t)35651584)
// persistent
#define F_X1       ((size_t)49283072)
#define F_XF       ((size_t)53477376)
#define F_PROBS    ((size_t)57671680)
#define F_INDS     ((size_t)57679872)
#define F_KEEP     ((size_t)57688064)
#define F_FLAT     ((size_t)57696256)

__device__ __forceinline__ ushort f2h(float f) {
    _Float16 h = (_Float16)f;
    union { _Float16 h; ushort u; } c; c.h = h; return c.u;
}
__device__ __forceinline__ float h2f(ushort u) {
    union { ushort u; _Float16 h; } c; c.u = u; return (float)c.h;
}
__device__ __forceinline__ float gelu_exact(float x) {
    return 0.5f * x * (1.0f + erff(x * 0.7071067811865475f));
}

// async global->LDS, 16B per lane; lds dest = base + lane*16 (wave-uniform base)
__device__ __forceinline__ void gl16(const void* g, void* l) {
    __builtin_amdgcn_global_load_lds(
        (const __attribute__((address_space(1))) void*)g,
        (__attribute__((address_space(3))) void*)l, 16, 0, 0);
}

// ---------------- split fp32 -> (hi fp16, lo fp16 scaled by 2048) ----------------
__global__ __launch_bounds__(256) void split_f32(const float* __restrict__ x,
                                                 ushort* __restrict__ hi,
                                                 ushort* __restrict__ lo, int n4) {
    int i = blockIdx.x * 256 + threadIdx.x;
    if (i >= n4) return;
    float4 v = ((const float4*)x)[i];
    float vv[4] = {v.x, v.y, v.z, v.w};
    ushort h[4], l[4];
#pragma unroll
    for (int e = 0; e < 4; e++) {
        h[e] = f2h(vv[e]);
        l[e] = f2h((vv[e] - h2f(h[e])) * LSCALE);
    }
    ((ushort4*)hi)[i] = make_ushort4(h[0], h[1], h[2], h[3]);
    ((ushort4*)lo)[i] = make_ushort4(l[0], l[1], l[2], l[3]);
}

// ---------------- LayerNorm: optional fp32 / fp16-hi / fp16-lo outputs ----------------
__global__ __launch_bounds__(256) void ln_kernel(const float* __restrict__ x,
                                                 const float* __restrict__ g,
                                                 const float* __restrict__ b,
                                                 float* __restrict__ yf,
                                                 ushort* __restrict__ yhi,
                                                 ushort* __restrict__ ylo) {
    __shared__ float red0[4], red1[4], bc[2];
    const size_t t = blockIdx.x;
    const float* row = x + t * DIM;
    float v[4];
    float s = 0.f, s2 = 0.f;
#pragma unroll
    for (int i = 0; i < 4; i++) {
        float vv = row[threadIdx.x + i * 256];
        v[i] = vv; s += vv; s2 += vv * vv;
    }
#pragma unroll
    for (int off = 32; off > 0; off >>= 1) {
        s  += __shfl_down(s, off);
        s2 += __shfl_down(s2, off);
    }
    const int lane = threadIdx.x & 63, wid = threadIdx.x >> 6;
    if (lane == 0) { red0[wid] = s; red1[wid] = s2; }
    __syncthreads();
    if (threadIdx.x == 0) {
        float S = red0[0] + red0[1] + red0[2] + red0[3];
        float S2 = red1[0] + red1[1] + red1[2] + red1[3];
        float mean = S * (1.0f / DIM);
        float var = S2 * (1.0f / DIM) - mean * mean;
        bc[0] = mean; bc[1] = rsqrtf(var + 1e-5f);
    }
    __syncthreads();
    const float mean = bc[0], r = bc[1];
#pragma unroll
    for (int i = 0; i < 4; i++) {
        int idx = threadIdx.x + i * 256;
        float val = (v[i] - mean) * r * g[idx] + b[idx];
        size_t o = t * DIM + idx;
        if (yf) yf[o] = val;
        if (yhi) {
            ushort h = f2h(val);
            yhi[o] = h;
            if (ylo) ylo[o] = f2h((val - h2f(h)) * LSCALE);
        }
    }
}

// ---------------- fp16 MFMA NT GEMM; SPLIT = scaled hi/lo (fp32-accurate) ----------------
// Staging: global_load_lds (16B/lane DMA) into linear [128][32] LDS tiles.
// Bank-conflict fix (rule 21): chunk_phys = chunk_log ^ ((row>>1)&3); inverse applied
// on per-lane global source, forward applied on fragment reads -> 2-way (free).
template<bool SPLIT>
__global__ __launch_bounds__(256) void gemm_ht(
    const ushort* __restrict__ Ahi, const ushort* __restrict__ Alo, int lda, long long sA,
    const ushort* __restrict__ Bhi, const ushort* __restrict__ Blo, int ldb, long long sB,
    const float* __restrict__ bias, long long sBias,
    const float* __restrict__ resid, int ldr,
    float* __restrict__ outf, ushort* __restrict__ outhi, ushort* __restrict__ outlo,
    int ldc, long long sC, int Kdim, int act, int accum) {
    __shared__ ushort sAh[128][32];
    __shared__ ushort sBh[128][32];
    __shared__ ushort sAl[SPLIT ? 128 : 1][32];
    __shared__ ushort sBl[SPLIT ? 128 : 1][32];
    const int z = blockIdx.z;
    Ahi += (size_t)z * sA; Bhi += (size_t)z * sB;
    if constexpr (SPLIT) { Alo += (size_t)z * sA; Blo += (size_t)z * sB; }
    if (bias) bias += (size_t)z * sBias;
    if (outf) outf += (size_t)z * sC;
    if (outhi) outhi += (size_t)z * sC;
    if (outlo) outlo += (size_t)z * sC;

    const int tid = threadIdx.x;
    const int row0 = blockIdx.y * 128, col0 = blockIdx.x * 128;
    const int lane = tid & 63;
    const int m = lane & 15, half = lane >> 4;
    const int w = tid >> 6;
    const int ar0 = (w >> 1) * 64, bc0 = (w & 1) * 64;

    // staging geometry: wave w covers rows [w*32, w*32+32); lane l -> row w*32+(l>>2),
    // phys chunk l&3. Source pre-swizzle: logical chunk = (l&3) ^ ((row>>1)&3) = (l&3)^((l>>3)&3).
    const int srow = w * 32 + (lane >> 2);                 // round-0 row (round-1 = +16)
    const int ssw  = (((lane >> 3) & 3) ^ (lane & 3)) * 8; // ushort offset of logical chunk
    // fragment-read swizzle: chunk = half ^ ((fragrow>>1)&3) = half ^ ((m>>1)&3)
    const int rsw8 = ((((m >> 1) & 3) ^ half)) * 8;

    floatx4 acc[4][4];
    floatx4 acc2[SPLIT ? 4 : 1][SPLIT ? 4 : 1];
#pragma unroll
    for (int i = 0; i < 4; i++)
#pragma unroll
        for (int j = 0; j < 4; j++) acc[i][j] = (floatx4){0.f, 0.f, 0.f, 0.f};
    if constexpr (SPLIT) {
#pragma unroll
        for (int i = 0; i < 4; i++)
#pragma unroll
            for (int j = 0; j < 4; j++) acc2[i][j] = (floatx4){0.f, 0.f, 0.f, 0.f};
    }

    for (int k0 = 0; k0 < Kdim; k0 += 32) {
        __syncthreads();   // previous tile fully consumed before DMA overwrite
        {
            const ushort* gA = Ahi + (size_t)(row0 + srow) * lda + k0 + ssw;
            const ushort* gB = Bhi + (size_t)(col0 + srow) * ldb + k0 + ssw;
            gl16(gA,                      &sAh[w * 32][0]);
            gl16(gA + (size_t)16 * lda,   &sAh[w * 32 + 16][0]);
            gl16(gB,                      &sBh[w * 32][0]);
            gl16(gB + (size_t)16 * ldb,   &sBh[w * 32 + 16][0]);
            if constexpr (SPLIT) {
                const ushort* gAl = Alo + (size_t)(row0 + srow) * lda + k0 + ssw;
                const ushort* gBl = Blo + (size_t)(col0 + srow) * ldb + k0 + ssw;
                gl16(gAl,                    &sAl[w * 32][0]);
                gl16(gAl + (size_t)16 * lda, &sAl[w * 32 + 16][0]);
                gl16(gBl,                    &sBl[w * 32][0]);
                gl16(gBl + (size_t)16 * ldb, &sBl[w * 32 + 16][0]);
            }
        }
        __syncthreads();   // compiler-emitted vmcnt(0) drain: tile ready
        half8 fa[4], fb[4], fal[4], fbl[4];
#pragma unroll
        for (int i = 0; i < 4; i++) fa[i] = *(const half8*)&sAh[ar0 + i * 16 + m][rsw8];
#pragma unroll
        for (int j = 0; j < 4; j++) fb[j] = *(const half8*)&sBh[bc0 + j * 16 + m][rsw8];
        if constexpr (SPLIT) {
#pragma unroll
            for (int i = 0; i < 4; i++) fal[i] = *(const half8*)&sAl[ar0 + i * 16 + m][rsw8];
#pragma unroll
            for (int j = 0; j < 4; j++) fbl[j] = *(const half8*)&sBl[bc0 + j * 16 + m][rsw8];
        }
#pragma unroll
        for (int i = 0; i < 4; i++)
#pragma unroll
            for (int j = 0; j < 4; j++) {
                acc[i][j] = __builtin_amdgcn_mfma_f32_16x16x32_f16(fa[i], fb[j], acc[i][j], 0, 0, 0);
                if constexpr (SPLIT) {
                    acc2[i][j] = __builtin_amdgcn_mfma_f32_16x16x32_f16(fa[i], fbl[j], acc2[i][j], 0, 0, 0);
                    acc2[i][j] = __builtin_amdgcn_mfma_f32_16x16x32_f16(fal[i], fb[j], acc2[i][j], 0, 0, 0);
                }
            }
    }
    // epilogue: C/D layout col=lane&15, row=(lane>>4)*4+reg
#pragma unroll
    for (int i = 0; i < 4; i++) {
#pragma unroll
        for (int j = 0; j < 4; j++) {
            const int col = col0 + bc0 + j * 16 + m;
            const float bv = bias ? bias[col] : 0.f;
#pragma unroll
            for (int r = 0; r < 4; r++) {
                const int row = row0 + ar0 + i * 16 + half * 4 + r;
                float v = acc[i][j][r];
                if constexpr (SPLIT) v += acc2[i][j][r] * INV_LSCALE;
                v += bv;
                if (resid) v += resid[(size_t)row * ldr + col];
                if (accum) v += outf[(size_t)row * ldc + col];
                if (act) v = gelu_exact(v);
                const size_t o = (size_t)row * ldc + col;
                if (outf) outf[o] = v;
                if (outhi) {
                    ushort h = f2h(v);
                    outhi[o] = h;
                    if (outlo) outlo[o] = f2h((v - h2f(h)) * LSCALE);
                }
            }
        }
    }
}

// ---------------- transpose fp32 [R,C] -> fp16 [C,R], batched ----------------
__global__ __launch_bounds__(256) void transpose_h(const float* __restrict__ in, long long sIn, int ldin,
                                                   ushort* __restrict__ out, long long sOut, int ldout) {
    __shared__ float t[32][33];
    const int z = blockIdx.z;
    in += (size_t)z * sIn; out += (size_t)z * sOut;
    const int cx = threadIdx.x & 31, ry = threadIdx.x >> 5;
    const int r0 = blockIdx.y * 32, c0 = blockIdx.x * 32;
#pragma unroll
    for (int rr = 0; rr < 4; rr++)
        t[ry + rr * 8][cx] = in[(size_t)(r0 + ry + rr * 8) * ldin + c0 + cx];
    __syncthreads();
#pragma unroll
    for (int rr = 0; rr < 4; rr++)
        out[(size_t)(c0 + ry + rr * 8) * ldout + r0 + cx] = f2h(t[cx][ry + rr * 8]);
}

// ---------------- V^T builder: v_hi/v_lo [4096][1024] -> vT [64 bh][64 d][1024 s] ----------------
__global__ __launch_bounds__(256) void vtrans_kernel(const ushort* __restrict__ vhi,
                                                     const ushort* __restrict__ vlo,
                                                     ushort* __restrict__ vthi,
                                                     ushort* __restrict__ vtlo) {
    __shared__ ushort th[32][72], tl[32][72];
    const int bh = blockIdx.y, b = bh >> 4, h = bh & 15;
    const int s0 = blockIdx.x * 32;
    const int t = threadIdx.x;
    {
        const int s = t >> 3, d0 = (t & 7) * 8;
        const size_t src = ((size_t)(b * 1024 + s0 + s)) * 1024 + h * 64 + d0;
        *(uint4*)&th[s][d0] = *(const uint4*)&vhi[src];
        *(uint4*)&tl[s][d0] = *(const uint4*)&vlo[src];
    }
    __syncthreads();
    {
        const int d = t >> 2, soff = (t & 3) * 8;
        us8 rh, rl;
#pragma unroll
        for (int e = 0; e < 8; e++) { rh[e] = th[soff + e][d]; rl[e] = tl[soff + e][d]; }
        const size_t dst = (size_t)bh * 65536 + (size_t)d * 1024 + s0 + soff;
        *(us8*)&vthi[dst] = rh;
        *(us8*)&vtlo[dst] = rl;
    }
}

// ---------------- causal flash attention, split fp16 MFMA (fp32-accurate) ----------------
// 128 q-rows/block, 4 waves x 32 rows, K-tiles of 64. K/V^T tiles staged into LDS
// via global_load_lds (wave w stages one matrix; XOR chunk swizzle, inverse on the
// per-lane DMA source). Uniform barrier tile loop; per-wave compute skip.
// Grid: (bh=64, qt=8) so a bh's blocks share an XCD (blockid mod 8 constant).
__global__ __launch_bounds__(256, 2) void attn_mfma(
        const ushort* __restrict__ qh_, const ushort* __restrict__ ql_,
        const ushort* __restrict__ kh_, const ushort* __restrict__ kl_,
        const ushort* __restrict__ vth_, const ushort* __restrict__ vtl_,
        ushort* __restrict__ ao_hi, ushort* __restrict__ ao_lo) {
    __shared__ ushort Ksh[64][64], Ksl[64][64], Vsh[64][64], Vsl[64][64]; // 32KB staged K/V^T
    __shared__ ushort plds[4][2][2048];   // [wave][hi/lo][32 rows x 64 cols, xor-swizzled]
    const int bh = blockIdx.x;
    const int b = bh >> 4;
    const int qt = 7 - blockIdx.y;        // high-work tiles dispatch first
    const int tid = threadIdx.x;
    const int w = tid >> 6, lane = tid & 63;
    const int m = lane & 15, hq = lane >> 4;
    const int wrow = qt * 128 + w * 32;   // global q-row base of this wave (within b)
    const size_t cbase = ((size_t)b * 1024) * 1024 + (size_t)(bh & 15) * 64;
    const size_t vtbase = (size_t)bh * 65536;

    // staging lane geometry: lane l -> row (l>>3) within 8-row DMA group, phys chunk l&7;
    // source pre-swizzle: logical chunk = (l&7) ^ ((l>>3)&7)
    const int srr = lane >> 3;
    const int scs = ((lane & 7) ^ (srr & 7)) * 8;   // ushort offset of logical chunk
    // fragment-read swizzle: phys chunk = (kk*4+hq) ^ (row&7), row&7 = m&7
    const int rs0 = ((hq ^ (m & 7)) & 7) * 8;          // kk=0
    const int rs1 = (((4 + hq) ^ (m & 7)) & 7) * 8;    // kk=1

    // Q fragments (persistent): lane holds Q[wrow+i*16+m][kk*32+hq*8 ..+7]
    half8 qfh[2][2], qfl[2][2];
#pragma unroll
    for (int i = 0; i < 2; i++)
#pragma unroll
        for (int kk = 0; kk < 2; kk++) {
            const size_t o = cbase + (size_t)(wrow + i * 16 + m) * 1024 + kk * 32 + hq * 8;
            qfh[i][kk] = *(const half8*)&qh_[o];
            qfl[i][kk] = *(const half8*)&ql_[o];
        }

    floatx4 accO[2][4], accO2[2][4];
#pragma unroll
    for (int i = 0; i < 2; i++)
#pragma unroll
        for (int d = 0; d < 4; d++) {
            accO[i][d] = (floatx4){0.f, 0.f, 0.f, 0.f};
            accO2[i][d] = (floatx4){0.f, 0.f, 0.f, 0.f};
        }
    float mx[2][4], ls[2][4];
#pragma unroll
    for (int i = 0; i < 2; i++)
#pragma unroll
        for (int r = 0; r < 4; r++) { mx[i][r] = -3.0e38f; ls[i][r] = 0.f; }

    const int NT = 2 * qt + 2;            // block-uniform tile count
    for (int t = 0; t < NT; t++) {
        const int j0 = t * 64;
        // ---- cooperative staging: wave w stages one 64x64 matrix (8 DMAs) ----
        __syncthreads();   // previous tile fully consumed
        if (w == 0) {
            const ushort* g = kh_ + cbase + (size_t)(j0 + srr) * 1024 + scs;
#pragma unroll
            for (int dma = 0; dma < 8; dma++)
                gl16(g + (size_t)dma * 8 * 1024, &Ksh[dma * 8][0]);
        } else if (w == 1) {
            const ushort* g = kl_ + cbase + (size_t)(j0 + srr) * 1024 + scs;
#pragma unroll
            for (int dma = 0; dma < 8; dma++)
                gl16(g + (size_t)dma * 8 * 1024, &Ksl[dma * 8][0]);
        } else if (w == 2) {
            const ushort* g = vth_ + vtbase + (size_t)srr * 1024 + j0 + scs;
#pragma unroll
            for (int dma = 0; dma < 8; dma++)
                gl16(g + (size_t)dma * 8 * 1024, &Vsh[dma * 8][0]);
        } else {
            const ushort* g = vtl_ + vtbase + (size_t)srr * 1024 + j0 + scs;
#pragma unroll
            for (int dma = 0; dma < 8; dma++)
                gl16(g + (size_t)dma * 8 * 1024, &Vsl[dma * 8][0]);
        }
        __syncthreads();   // vmcnt drained: tile ready
        if (j0 > wrow + 31) continue;   // fully masked for this wave (barriers stay uniform)

        // ---- QK^T: S = Qh*Kh + (Qh*Kl + Ql*Kh)/2048 ----
        floatx4 accS[2][4], accS2[2][4];
#pragma unroll
        for (int i = 0; i < 2; i++)
#pragma unroll
            for (int jf = 0; jf < 4; jf++) {
                accS[i][jf] = (floatx4){0.f, 0.f, 0.f, 0.f};
                accS2[i][jf] = (floatx4){0.f, 0.f, 0.f, 0.f};
            }
#pragma unroll
        for (int kk = 0; kk < 2; kk++) {
            const int rsw = kk ? rs1 : rs0;
            half8 kfh[4], kfl[4];
#pragma unroll
            for (int jf = 0; jf < 4; jf++) {
                kfh[jf] = *(const half8*)&Ksh[jf * 16 + m][rsw];
                kfl[jf] = *(const half8*)&Ksl[jf * 16 + m][rsw];
            }
#pragma unroll
            for (int i = 0; i < 2; i++)
#pragma unroll
                for (int jf = 0; jf < 4; jf++) {
                    accS[i][jf] = __builtin_amdgcn_mfma_f32_16x16x32_f16(qfh[i][kk], kfh[jf], accS[i][jf], 0, 0, 0);
                    accS2[i][jf] = __builtin_amdgcn_mfma_f32_16x16x32_f16(qfh[i][kk], kfl[jf], accS2[i][jf], 0, 0, 0);
                    accS2[i][jf] = __builtin_amdgcn_mfma_f32_16x16x32_f16(qfl[i][kk], kfh[jf], accS2[i][jf], 0, 0, 0);
                }
        }
        // ---- combine, scale, causal mask ----
        const bool diag = (j0 + 63 > wrow);
        float p[2][4][4];
#pragma unroll
        for (int i = 0; i < 2; i++)
#pragma unroll
            for (int jf = 0; jf < 4; jf++)
#pragma unroll
                for (int r = 0; r < 4; r++) {
                    float s = (accS[i][jf][r] + accS2[i][jf][r] * INV_LSCALE) * 0.125f;
                    if (diag && (j0 + jf * 16 + m > wrow + i * 16 + hq * 4 + r)) s = -3.0e38f;
                    p[i][jf][r] = s;
                }
        // ---- online softmax per row; rows live in the same (hq,r) lanes as O ----
#pragma unroll
        for (int i = 0; i < 2; i++)
#pragma unroll
            for (int r = 0; r < 4; r++) {
                float tm = fmaxf(fmaxf(p[i][0][r], p[i][1][r]), fmaxf(p[i][2][r], p[i][3][r]));
#pragma unroll
                for (int off = 8; off > 0; off >>= 1) tm = fmaxf(tm, __shfl_xor(tm, off));
                const float mn = fmaxf(mx[i][r], tm);
                const float c = __expf(mx[i][r] - mn);
                mx[i][r] = mn;
                float rs = 0.f;
#pragma unroll
                for (int jf = 0; jf < 4; jf++) {
                    const float e = __expf(p[i][jf][r] - mn);
                    p[i][jf][r] = e;
                    rs += e;
                }
#pragma unroll
                for (int off = 8; off > 0; off >>= 1) rs += __shfl_xor(rs, off);
                ls[i][r] = ls[i][r] * c + rs;
#pragma unroll
                for (int d = 0; d < 4; d++) { accO[i][d][r] *= c; accO2[i][d][r] *= c; }
            }
        // ---- P -> LDS (hi/lo, xor-swizzled rows) ----
#pragma unroll
        for (int i = 0; i < 2; i++)
#pragma unroll
            for (int jf = 0; jf < 4; jf++)
#pragma unroll
                for (int r = 0; r < 4; r++) {
                    const int row = i * 16 + hq * 4 + r;
                    const int idx = row * 64 + ((jf * 16 + m) ^ ((row & 7) << 3));
                    const float pv = p[i][jf][r];
                    const ushort hh = f2h(pv);
                    plds[w][0][idx] = hh;
                    plds[w][1][idx] = f2h((pv - h2f(hh)) * LSCALE);
                }
        // ---- PV: O += Ph*Vh + (Ph*Vl + Pl*Vh)/2048 ----
#pragma unroll
        for (int kk = 0; kk < 2; kk++) {
            const int rsw = kk ? rs1 : rs0;
            half8 pfh[2], pfl[2], vfh[4], vfl[4];
#pragma unroll
            for (int i = 0; i < 2; i++) {
                const int row = i * 16 + m;
                const int idx = row * 64 + ((kk * 32 + hq * 8) ^ ((row & 7) << 3));
                pfh[i] = *(const half8*)&plds[w][0][idx];
                pfl[i] = *(const half8*)&plds[w][1][idx];
            }
#pragma unroll
            for (int d = 0; d < 4; d++) {
                vfh[d] = *(const half8*)&Vsh[d * 16 + m][rsw];
                vfl[d] = *(const half8*)&Vsl[d * 16 + m][rsw];
            }
#pragma unroll
            for (int i = 0; i < 2; i++)
#pragma unroll
                for (int d = 0; d < 4; d++) {
                    accO[i][d] = __builtin_amdgcn_mfma_f32_16x16x32_f16(pfh[i], vfh[d], accO[i][d], 0, 0, 0);
                    accO2[i][d] = __builtin_amdgcn_mfma_f32_16x16x32_f16(pfh[i], vfl[d], accO2[i][d], 0, 0, 0);
                    accO2[i][d] = __builtin_amdgcn_mfma_f32_16x16x32_f16(pfl[i], vfh[d], accO2[i][d], 0, 0, 0);
                }
        }
    }
    // ---- epilogue: normalize + write hi/lo ----
#pragma unroll
    for (int i = 0; i < 2; i++)
#pragma unroll
        for (int r = 0; r < 4; r++) {
            const float inv = 1.f / ls[i][r];
            const size_t rb = cbase + (size_t)(wrow + i * 16 + hq * 4 + r) * 1024;
#pragma unroll
            for (int d = 0; d < 4; d++) {
                const float v = (accO[i][d][r] + accO2[i][d][r] * INV_LSCALE) * inv;
                const ushort hh = f2h(v);
                const size_t o = rb + d * 16 + m;
                ao_hi[o] = hh;
                ao_lo[o] = f2h((v - h2f(hh)) * LSCALE);
            }
        }
}

// ---------------- router second GEMM + top-2 + softmax probs (pure fp32) ----------------
__global__ __launch_bounds__(256) void router2_kernel(const float* __restrict__ h1,
                                                      const float* __restrict__ w2,
                                                      const float* __restrict__ b2,
                                                      float* __restrict__ logits_out,
                                                      float* __restrict__ probs,
                                                      int* __restrict__ inds) {
    __shared__ float red[16][4];
    __shared__ float lg[16];
    const int t = blockIdx.x;
    const float* hrow = h1 + (size_t)t * HMLP;
    float acc[16];
#pragma unroll
    for (int m = 0; m < 16; m++) acc[m] = 0.f;
    for (int i = 0; i < 16; i++) {
        int kk = threadIdx.x + i * 256;
        float hv = hrow[kk];
#pragma unroll
        for (int m = 0; m < 16; m++) acc[m] = fmaf(hv, w2[m * HMLP + kk], acc[m]);
    }
#pragma unroll
    for (int m = 0; m < 16; m++)
#pragma unroll
        for (int off = 32; off > 0; off >>= 1) acc[m] += __shfl_down(acc[m], off);
    const int lane = threadIdx.x & 63, wid = threadIdx.x >> 6;
    if (lane == 0) {
#pragma unroll
        for (int m = 0; m < 16; m++) red[m][wid] = acc[m];
    }
    __syncthreads();
    if (threadIdx.x < 16) {
        float v = red[threadIdx.x][0] + red[threadIdx.x][1] + red[threadIdx.x][2] + red[threadIdx.x][3]
                  + b2[threadIdx.x];
        lg[threadIdx.x] = v;
        logits_out[(size_t)t * 16 + threadIdx.x] = v;
    }
    __syncthreads();
    if (threadIdx.x == 0) {
        int i0 = 0; float v0 = lg[0];
        for (int m = 1; m < 16; m++) if (lg[m] > v0) { v0 = lg[m]; i0 = m; }
        int i1 = -1; float v1 = -3.4e38f;
        for (int m = 0; m < 16; m++) if (m != i0 && lg[m] > v1) { v1 = lg[m]; i1 = m; }
        float e1 = expf(v1 - v0);
        float den = 1.f + e1;
        inds[2 * t] = i0; inds[2 * t + 1] = i1;
        probs[2 * t] = 1.f / den; probs[2 * t + 1] = e1 / den;
    }
}

// ---------------- capacity scan ----------------
__global__ __launch_bounds__(256) void scan_kernel(const int* __restrict__ inds,
                                                   int* __restrict__ keep,
                                                   int* __restrict__ flat) {
    __shared__ int counts[256][16];
    const int t = threadIdx.x;
#pragma unroll
    for (int e = 0; e < 16; e++) counts[t][e] = 0;
    const int base = t * 32;
    for (int i = 0; i < 32; i++) counts[t][inds[base + i]]++;
    __syncthreads();
    if (t < 16) {
        int run = 0;
        for (int c = 0; c < 256; c++) { int tmp = counts[c][t]; counts[c][t] = run; run += tmp; }
    }
    __syncthreads();
    for (int i = 0; i < 32; i++) {
        int e = inds[base + i];
        int p = counts[t][e]++;
        keep[base + i] = (p < CAP) ? 1 : 0;
        flat[base + i] = e * CAP + p;
    }
}

// ---------------- scatter tokens (fp32 xf -> fp16 expert_in) ----------------
__global__ __launch_bounds__(256) void scatter_kernel(const float* __restrict__ xf,
                                                      const int* __restrict__ keep,
                                                      const int* __restrict__ flat,
                                                      ushort* __restrict__ expert_in) {
    const int e = blockIdx.x;
    if (!keep[e]) return;
    const int token = e >> 1;
    const float* src = xf + (size_t)token * DIM;
    ushort* dst = expert_in + (size_t)flat[e] * DIM;
#pragma unroll
    for (int i = 0; i < 4; i++) dst[threadIdx.x + i * 256] = f2h(src[threadIdx.x + i * 256]);
}

// ---------------- combine ----------------
__global__ __launch_bounds__(256) void combine_kernel(const float* __restrict__ x1,
                                                      const float* __restrict__ xf,
                                                      const float* __restrict__ eout,
                                                      const float* __restrict__ probs,
                                                      const int* __restrict__ keep,
                                                      const int* __restrict__ flat,
                                                      float* __restrict__ out) {
    const int t = blockIdx.x;
    const int k0 = keep[2 * t], k1 = keep[2 * t + 1];
    const float p0 = probs[2 * t], p1 = probs[2 * t + 1];
    const size_t f0 = (size_t)flat[2 * t] * DIM, f1 = (size_t)flat[2 * t + 1] * DIM;
    const bool has = (k0 || k1);
    const size_t base = (size_t)t * DIM;
#pragma unroll
    for (int i = 0; i < 4; i++) {
        const int idx = threadIdx.x + i * 256;
        float mo;
        if (has) {
            mo = 0.f;
            if (k0) mo += p0 * eout[f0 + idx];
            if (k1) mo += p1 * eout[f1 + idx];
        } else {
            mo = xf[base + idx];
        }
        out[base + idx] = x1[base + idx] + mo;
    }
}

extern "C" void kernel_launch(void* const* d_in, const int* in_sizes, int n_in,
                              void* d_out, int out_size, void* d_ws, size_t ws_size,
                              hipStream_t stream) {
    const float* x          = (const float*)d_in[0];
    const float* ln1_g      = (const float*)d_in[1];
    const float* ln1_b      = (const float*)d_in[2];
    const float* qkv_w      = (const float*)d_in[3];
    const float* qkv_b      = (const float*)d_in[4];
    const float* attn_in_w  = (const float*)d_in[5];
    const float* attn_in_b  = (const float*)d_in[6];
    const float* attn_out_w = (const float*)d_in[7];
    const float* attn_out_b = (const float*)d_in[8];
    const float* ln2_g      = (const float*)d_in[9];
    const float* ln2_b      = (const float*)d_in[10];
    const float* r_w1       = (const float*)d_in[11];
    const float* r_b1       = (const float*)d_in[12];
    const float* r_w2       = (const float*)d_in[13];
    const float* r_b2       = (const float*)d_in[14];
    const float* mlp1       = (const float*)d_in[15];
    const float* mlp2       = (const float*)d_in[16];

    float* ws = (float*)d_ws;
    ushort* qkv_hi   = (ushort*)(ws + F_QKV_HI);
    ushort* qkv_lo   = (ushort*)(ws + F_QKV_LO);
    ushort* xn_hi    = (ushort*)(ws + F_XN_HI);
    ushort* xn_lo    = (ushort*)(ws + F_XN_LO);
    float*  h1       = ws + F_H1;
    float*  eout     = ws + F_EOUT;
    ushort* q_hi     = (ushort*)(ws + F_Q16_HI);
    ushort* q_lo     = (ushort*)(ws + F_Q16_LO);
    ushort* v_hi     = (ushort*)(ws + F_V16_HI);
    ushort* v_lo     = (ushort*)(ws + F_V16_LO);
    ushort* k_hi     = (ushort*)(ws + F_K16_HI);
    ushort* k_lo     = (ushort*)(ws + F_K16_LO);
    ushort* vt_hi    = (ushort*)(ws + F_VT_HI);
    ushort* vt_lo    = (ushort*)(ws + F_VT_LO);
    ushort* ao_hi    = (ushort*)(ws + F_AO_HI);
    ushort* ao_lo    = (ushort*)(ws + F_AO_LO);
    ushort* xf_hi    = (ushort*)(ws + F_XF_HI);
    ushort* xf_lo    = (ushort*)(ws + F_XF_LO);
    ushort* wqkv_hi  = (ushort*)(ws + F_WQKV_HI);
    ushort* wqkv_lo  = (ushort*)(ws + F_WQKV_LO);
    ushort* wain_hi  = (ushort*)(ws + F_WAIN_HI);
    ushort* wain_lo  = (ushort*)(ws + F_WAIN_LO);
    ushort* waout_hi = (ushort*)(ws + F_WAOUT_HI);
    ushort* waout_lo = (ushort*)(ws + F_WAOUT_LO);
    ushort* wr1_hi   = (ushort*)(ws + F_WR1_HI);
    ushort* wr1_lo   = (ushort*)(ws + F_WR1_LO);
    ushort* expert_in= (ushort*)(ws + F_EXPIN);
    ushort* mlp1t    = (ushort*)(ws + F_MLP1T);
    ushort* mid      = (ushort*)(ws + F_MID);
    ushort* mlp2t    = (ushort*)(ws + F_MLP2T);
    float*  x1       = ws + F_X1;
    float*  xf       = ws + F_XF;
    float*  probs    = ws + F_PROBS;
    int*    inds     = (int*)(ws + F_INDS);
    int*    keep     = (int*)(ws + F_KEEP);
    int*    flat     = (int*)(ws + F_FLAT);

    float* out        = (float*)d_out;
    float* logits_out = out + (size_t)NTOK * DIM;

    // weight splits (fp16 hi + scaled lo)
    split_f32<<<(3145728 / 4 + 255) / 256, 256, 0, stream>>>(qkv_w, wqkv_hi, wqkv_lo, 3145728 / 4);
    split_f32<<<(3145728 / 4 + 255) / 256, 256, 0, stream>>>(attn_in_w, wain_hi, wain_lo, 3145728 / 4);
    split_f32<<<(1048576 / 4 + 255) / 256, 256, 0, stream>>>(attn_out_w, waout_hi, waout_lo, 1048576 / 4);
    split_f32<<<(4194304 / 4 + 255) / 256, 256, 0, stream>>>(r_w1, wr1_hi, wr1_lo, 4194304 / 4);

    // 1. LN1 -> xn hi/lo
    ln_kernel<<<NTOK, 256, 0, stream>>>(x, ln1_g, ln1_b, nullptr, xn_hi, xn_lo);
    // 2. qkv = xn @ qkv_w.T + qkv_b   (split, out hi/lo)
    gemm_ht<true><<<dim3(H3 / 128, NTOK / 128, 1), 256, 0, stream>>>(
        xn_hi, xn_lo, DIM, 0, wqkv_hi, wqkv_lo, DIM, 0, qkv_b, 0,
        nullptr, 0, nullptr, qkv_hi, qkv_lo, H3, 0, DIM, 0, 0);
    // 3. q/k/v in-projections, batched z=3 (split, out fp16 hi/lo directly)
    gemm_ht<true><<<dim3(DIM / 128, NTOK / 128, 3), 256, 0, stream>>>(
        qkv_hi, qkv_lo, H3, 1024, wain_hi, wain_lo, DIM, 1048576, attn_in_b, 1024,
        nullptr, 0, nullptr, q_hi, q_lo, DIM, 4194304, DIM, 0, 0);
    // 3b. build V^T hi/lo per (b,h) for the PV B-operand
    vtrans_kernel<<<dim3(32, 64), 256, 0, stream>>>(v_hi, v_lo, vt_hi, vt_lo);
    // 4. MFMA flash attention -> ao hi/lo  (grid: bh-major for XCD L2 locality)
    attn_mfma<<<dim3(64, 8), 256, 0, stream>>>(q_hi, q_lo, k_hi, k_lo, vt_hi, vt_lo, ao_hi, ao_lo);
    // 5. x1 = x + ao @ attn_out_w.T + b  (split, out fp32)
    gemm_ht<true><<<dim3(DIM / 128, NTOK / 128, 1), 256, 0, stream>>>(
        ao_hi, ao_lo, DIM, 0, waout_hi, waout_lo, DIM, 0, attn_out_b, 0,
        x, DIM, x1, nullptr, nullptr, DIM, 0, DIM, 0, 0);
    // 6. LN2 -> xf fp32 + hi/lo
    ln_kernel<<<NTOK, 256, 0, stream>>>(x1, ln2_g, ln2_b, xf, xf_hi, xf_lo);
    // 7. h1 = gelu(xf @ r_w1.T + r_b1)  (split, out fp32)
    gemm_ht<true><<<dim3(HMLP / 128, NTOK / 128, 1), 256, 0, stream>>>(
        xf_hi, xf_lo, DIM, 0, wr1_hi, wr1_lo, DIM, 0, r_b1, 0,
        nullptr, 0, h1, nullptr, nullptr, HMLP, 0, DIM, 1, 0);
    // 8. router logits + top-2 (fp32)
    router2_kernel<<<NTOK, 256, 0, stream>>>(h1, r_w2, r_b2, logits_out, probs, inds);
    // 9. capacity scan
    scan_kernel<<<1, 256, 0, stream>>>(inds, keep, flat);
    // 10. scatter (fp32 xf -> fp16 expert buffers)
    scatter_kernel<<<NTOK * 2, 256, 0, stream>>>(xf, keep, flat, expert_in);
    // 11. expert FFN, fp16 MFMA, H chunked (transpose weights per chunk)
    for (int c = 0; c < HMLP / HCHUNK; c++) {
        transpose_h<<<dim3(32, 32, NEXP), 256, 0, stream>>>(
            mlp1 + (size_t)c * HCHUNK, (long long)DIM * HMLP, HMLP, mlp1t, 1048576, DIM);
        gemm_ht<false><<<dim3(HCHUNK / 128, CAP / 128, NEXP), 256, 0, stream>>>(
            expert_in, nullptr, DIM, 655360, mlp1t, nullptr, DIM, 1048576, nullptr, 0,
            nullptr, 0, nullptr, mid, nullptr, HCHUNK, 655360, DIM, 1, 0);
        transpose_h<<<dim3(32, 32, NEXP), 256, 0, stream>>>(
            mlp2 + (size_t)c * HCHUNK * DIM, (long long)HMLP * DIM, DIM, mlp2t, 1048576, HCHUNK);
        gemm_ht<false><<<dim3(DIM / 128, CAP / 128, NEXP), 256, 0, stream>>>(
            mid, nullptr, HCHUNK, 655360, mlp2t, nullptr, HCHUNK, 1048576, nullptr, 0,
            nullptr, 0, eout, nullptr, nullptr, DIM, 655360, HCHUNK, 0, c > 0);
    }
    // 12. combine + residual
    combine_kernel<<<NTOK, 256, 0, stream>>>(x1, xf, eout, probs, keep, flat, out);
}